// Round 1
// baseline (1013.171 us; speedup 1.0000x reference)
//
#include <hip/hip_runtime.h>
#include <math.h>

#define LUT_D 33
#define LUT_D3 35937   // 33^3
#define NEG 0.2f
#define BATCH 4
#define HW_IMG 1048576 // 1024*1024

// ---------------- resize 1024 -> 256 (half-pixel bilinear, scale 4 => frac=0.5) -------------
__global__ void k_resize(const float* __restrict__ lq, float* __restrict__ out) {
    int gid = blockIdx.x * 256 + threadIdx.x;     // over 4*3*256*256 = 786432
    if (gid >= BATCH * 3 * 256 * 256) return;
    int x  = gid & 255;
    int y  = (gid >> 8) & 255;
    int pc = gid >> 16;                            // b*3 + c
    const float* in = lq + (size_t)pc * HW_IMG;
    const float* p0 = in + (4 * y + 1) * 1024 + (4 * x + 1);
    out[gid] = 0.25f * (p0[0] + p0[1] + p0[1024] + p0[1025]);
}

// ---------------- fused conv3x3 s2 p1 + LeakyReLU + InstanceNorm ----------------------------
// one workgroup (256 threads) per (b, oc) output plane
template<int IC, int OC, int OH, int OW, int PXT, bool DO_IN>
__global__ void k_conv(const float* __restrict__ in, const float* __restrict__ w,
                       const float* __restrict__ bias,
                       const float* __restrict__ gamma, const float* __restrict__ beta,
                       float* __restrict__ out) {
    const int IH = OH * 2, IW = OW * 2;
    int b  = blockIdx.x / OC;
    int oc = blockIdx.x % OC;
    __shared__ float wl[IC * 9];
    __shared__ float red[256];
    for (int i = threadIdx.x; i < IC * 9; i += 256) wl[i] = w[oc * IC * 9 + i];
    __syncthreads();
    const float* inb = in + (size_t)b * IC * IH * IW;
    float v[PXT];
    float s1 = 0.f, s2 = 0.f;
    float bi = bias[oc];
    for (int i = 0; i < PXT; i++) {
        int p  = threadIdx.x + i * 256;
        int oy = p / OW, ox = p % OW;
        int iy0 = 2 * oy - 1, ix0 = 2 * ox - 1;
        float acc = bi;
        for (int ic = 0; ic < IC; ic++) {
            const float* ip = inb + (size_t)ic * IH * IW;
            const float* wp = wl + ic * 9;
            #pragma unroll
            for (int ky = 0; ky < 3; ky++) {
                int iy = iy0 + ky;
                if (iy < 0 || iy >= IH) continue;
                #pragma unroll
                for (int kx = 0; kx < 3; kx++) {
                    int ix = ix0 + kx;
                    if (ix < 0 || ix >= IW) continue;
                    acc += ip[iy * IW + ix] * wp[ky * 3 + kx];
                }
            }
        }
        acc = acc >= 0.f ? acc : NEG * acc;
        v[i] = acc;
        s1 += acc; s2 += acc * acc;
    }
    float* ob = out + ((size_t)b * OC + oc) * OH * OW;
    if (DO_IN) {
        red[threadIdx.x] = s1; __syncthreads();
        for (int s = 128; s > 0; s >>= 1) { if (threadIdx.x < s) red[threadIdx.x] += red[threadIdx.x + s]; __syncthreads(); }
        float m = red[0] * (1.f / (OH * OW));
        __syncthreads();
        red[threadIdx.x] = s2; __syncthreads();
        for (int s = 128; s > 0; s >>= 1) { if (threadIdx.x < s) red[threadIdx.x] += red[threadIdx.x + s]; __syncthreads(); }
        float var = red[0] * (1.f / (OH * OW)) - m * m;
        float sc = gamma[oc] * rsqrtf(var + 1e-5f);
        float sh = beta[oc] - m * sc;
        for (int i = 0; i < PXT; i++) ob[threadIdx.x + i * 256] = v[i] * sc + sh;
    } else {
        for (int i = 0; i < PXT; i++) ob[threadIdx.x + i * 256] = v[i];
    }
}

// ---------------- block5 (conv + leaky, no IN) fused with AdaptiveAvgPool2d(2) -> codes -----
// one workgroup (64 threads) per (b, oc); in [4,128,16,16], out codes [4,512]
__global__ void k_conv5_pool(const float* __restrict__ in, const float* __restrict__ w,
                             const float* __restrict__ bias, float* __restrict__ codes) {
    int b  = blockIdx.x / 128;
    int oc = blockIdx.x % 128;
    __shared__ float wl[128 * 9];
    __shared__ float vals[64];
    for (int i = threadIdx.x; i < 128 * 9; i += 64) wl[i] = w[oc * 128 * 9 + i];
    __syncthreads();
    int t = threadIdx.x;  // 64 threads, one output pixel each (8x8)
    int oy = t >> 3, ox = t & 7;
    const float* inb = in + (size_t)b * 128 * 256;
    int iy0 = 2 * oy - 1, ix0 = 2 * ox - 1;
    float acc = bias[oc];
    for (int ic = 0; ic < 128; ic++) {
        const float* ip = inb + ic * 256;
        const float* wp = wl + ic * 9;
        #pragma unroll
        for (int ky = 0; ky < 3; ky++) {
            int iy = iy0 + ky;
            if (iy < 0 || iy >= 16) continue;
            #pragma unroll
            for (int kx = 0; kx < 3; kx++) {
                int ix = ix0 + kx;
                if (ix < 0 || ix >= 16) continue;
                acc += ip[iy * 16 + ix] * wp[ky * 3 + kx];
            }
        }
    }
    acc = acc >= 0.f ? acc : NEG * acc;
    vals[t] = acc;
    __syncthreads();
    if (t < 4) {
        int py = t >> 1, px = t & 1;
        float s = 0.f;
        for (int dy = 0; dy < 4; dy++)
            for (int dx = 0; dx < 4; dx++)
                s += vals[(py * 4 + dy) * 8 + px * 4 + dx];
        codes[b * 512 + oc * 4 + t] = s * (1.f / 16.f);
    }
}

// ---------------- heads: weights = codes@lw.T+lb ; vertices = pad(cumsum(softmax(...))) ----
// blocks 0..11: (b,ch) interval rows; block 12: the 12 lut-weights
__global__ void k_head(const float* __restrict__ codes, const float* __restrict__ lw,
                       const float* __restrict__ lb, const float* __restrict__ aw,
                       const float* __restrict__ ab, float* __restrict__ wt,
                       float* __restrict__ vert, float* __restrict__ out_w,
                       float* __restrict__ out_v) {
    int blk = blockIdx.x;
    int t = threadIdx.x;  // 64 threads
    if (blk == 12) {
        if (t < 12) {
            int b = t / 3, j = t % 3;
            const float* c = codes + b * 512;
            const float* l = lw + j * 512;
            float s = lb[j];
            for (int k = 0; k < 512; k++) s += c[k] * l[k];
            wt[t] = s;
            out_w[t] = s;
        }
        return;
    }
    int b = blk / 3, ch = blk % 3;
    __shared__ float y[32];
    if (t < 32) {
        const float* c = codes + b * 512;
        const float* a = aw + (size_t)(ch * 32 + t) * 512;
        float s = ab[ch * 32 + t];
        for (int k = 0; k < 512; k++) s += c[k] * a[k];
        y[t] = s;
    }
    __syncthreads();
    if (t == 0) {
        float mx = y[0];
        for (int m = 1; m < 32; m++) mx = fmaxf(mx, y[m]);
        float e[32];
        float sum = 0.f;
        for (int m = 0; m < 32; m++) { e[m] = expf(y[m] - mx); sum += e[m]; }
        float inv = 1.f / sum;
        float cum = 0.f;
        float* vb = vert + (b * 3 + ch) * 33;
        float* ob = out_v + (b * 3 + ch) * 33;
        vb[0] = 0.f; ob[0] = 0.f;
        for (int m = 0; m < 32; m++) { cum += e[m] * inv; vb[m + 1] = cum; ob[m + 1] = cum; }
    }
}

// ---------------- LUT generation: luts[b] = bw @ wt[b], relayout to [D][D][D] x float4 -----
__global__ void k_lutgen(const float* __restrict__ bw, const float* __restrict__ wt,
                         float* __restrict__ luts4) {
    int gid = blockIdx.x * 256 + threadIdx.x;     // over 4*35937
    if (gid >= BATCH * LUT_D3) return;
    int b = gid / LUT_D3;
    int cell = gid - b * LUT_D3;
    float w0 = wt[b * 3], w1 = wt[b * 3 + 1], w2 = wt[b * 3 + 2];
    const float* r0 = bw + (size_t)(0 * LUT_D3 + cell) * 3;
    const float* r1 = bw + (size_t)(1 * LUT_D3 + cell) * 3;
    const float* r2 = bw + (size_t)(2 * LUT_D3 + cell) * 3;
    float4 o;
    o.x = r0[0] * w0 + r0[1] * w1 + r0[2] * w2;
    o.y = r1[0] * w0 + r1[1] * w1 + r1[2] * w2;
    o.z = r2[0] * w0 + r2[1] * w1 + r2[2] * w2;
    o.w = 0.f;
    ((float4*)luts4)[gid] = o;
}

// ---------------- per-pixel searchsorted + trilinear LUT sample ----------------------------
__device__ __forceinline__ void search1(const float* __restrict__ sv, int ch, float x,
                                        int& i0, float& f) {
    const float* v = sv + ch * LUT_D;
    int lo = 0, hi = LUT_D;
    while (lo < hi) { int mid = (lo + hi) >> 1; if (v[mid] <= x) lo = mid + 1; else hi = mid; }
    int idx = lo < 1 ? 1 : (lo > LUT_D - 1 ? LUT_D - 1 : lo);
    float vl = v[idx - 1], vh = v[idx];
    float fr = (x - vl) / (vh - vl + 1e-8f);
    float coord = (float)(idx - 1) + fr;
    coord = fminf(fmaxf(coord, 0.f), (float)(LUT_D - 1));
    i0 = (int)floorf(coord);
    if (i0 > LUT_D - 2) i0 = LUT_D - 2;
    f = coord - (float)i0;
}

__global__ void __launch_bounds__(256) k_transform(const float* __restrict__ lq,
                                                   const float* __restrict__ luts4,
                                                   const float* __restrict__ vert,
                                                   float* __restrict__ out) {
    int bimg = blockIdx.x >> 10;                  // 1024 blocks per image
    int blk  = blockIdx.x & 1023;
    __shared__ float sv[3 * LUT_D];
    if (threadIdx.x < 3 * LUT_D) sv[threadIdx.x] = vert[bimg * 3 * LUT_D + threadIdx.x];
    __syncthreads();
    int p0 = blk * 1024 + threadIdx.x * 4;        // 4 px per thread
    const float* lr = lq + (size_t)bimg * 3 * HW_IMG + p0;
    float4 r4 = *(const float4*)(lr);
    float4 g4 = *(const float4*)(lr + HW_IMG);
    float4 b4 = *(const float4*)(lr + 2 * HW_IMG);
    const float4* L = (const float4*)(luts4 + (size_t)bimg * LUT_D3 * 4);
    float rr[4] = {r4.x, r4.y, r4.z, r4.w};
    float gg[4] = {g4.x, g4.y, g4.z, g4.w};
    float bb[4] = {b4.x, b4.y, b4.z, b4.w};
    float ro[4], go[4], bo[4];
    #pragma unroll
    for (int i = 0; i < 4; i++) {
        int i0, j0, k0; float fr, fg, fb;
        search1(sv, 0, rr[i], i0, fr);
        search1(sv, 1, gg[i], j0, fg);
        search1(sv, 2, bb[i], k0, fb);
        int base = (i0 * LUT_D + j0) * LUT_D + k0;
        float4 q000 = L[base],        q001 = L[base + 1];
        float4 q010 = L[base + 33],   q011 = L[base + 34];
        float4 q100 = L[base + 1089], q101 = L[base + 1090];
        float4 q110 = L[base + 1122], q111 = L[base + 1123];
        float w000 = (1.f - fr) * (1.f - fg) * (1.f - fb), w001 = (1.f - fr) * (1.f - fg) * fb;
        float w010 = (1.f - fr) * fg * (1.f - fb),         w011 = (1.f - fr) * fg * fb;
        float w100 = fr * (1.f - fg) * (1.f - fb),         w101 = fr * (1.f - fg) * fb;
        float w110 = fr * fg * (1.f - fb),                 w111 = fr * fg * fb;
        float rx = q000.x*w000 + q001.x*w001 + q010.x*w010 + q011.x*w011
                 + q100.x*w100 + q101.x*w101 + q110.x*w110 + q111.x*w111;
        float ry = q000.y*w000 + q001.y*w001 + q010.y*w010 + q011.y*w011
                 + q100.y*w100 + q101.y*w101 + q110.y*w110 + q111.y*w111;
        float rz = q000.z*w000 + q001.z*w001 + q010.z*w010 + q011.z*w011
                 + q100.z*w100 + q101.z*w101 + q110.z*w110 + q111.z*w111;
        ro[i] = fminf(fmaxf(rx, 0.f), 1.f);
        go[i] = fminf(fmaxf(ry, 0.f), 1.f);
        bo[i] = fminf(fmaxf(rz, 0.f), 1.f);
    }
    float* op = out + (size_t)bimg * 3 * HW_IMG + p0;
    float4 o0 = {ro[0], ro[1], ro[2], ro[3]};
    float4 o1 = {go[0], go[1], go[2], go[3]};
    float4 o2 = {bo[0], bo[1], bo[2], bo[3]};
    *(float4*)(op) = o0;
    *(float4*)(op + HW_IMG) = o1;
    *(float4*)(op + 2 * HW_IMG) = o2;
}

extern "C" void kernel_launch(void* const* d_in, const int* in_sizes, int n_in,
                              void* d_out, int out_size, void* d_ws, size_t ws_size,
                              hipStream_t stream) {
    const float* lq  = (const float*)d_in[0];
    const float* w1  = (const float*)d_in[1];
    const float* b1  = (const float*)d_in[2];
    const float* g1  = (const float*)d_in[3];
    const float* be1 = (const float*)d_in[4];
    const float* w2  = (const float*)d_in[5];
    const float* b2  = (const float*)d_in[6];
    const float* g2  = (const float*)d_in[7];
    const float* be2 = (const float*)d_in[8];
    const float* w3  = (const float*)d_in[9];
    const float* b3  = (const float*)d_in[10];
    const float* g3  = (const float*)d_in[11];
    const float* be3 = (const float*)d_in[12];
    const float* w4  = (const float*)d_in[13];
    const float* b4  = (const float*)d_in[14];
    const float* g4  = (const float*)d_in[15];
    const float* be4 = (const float*)d_in[16];
    const float* w5  = (const float*)d_in[17];
    const float* b5  = (const float*)d_in[18];
    const float* lw  = (const float*)d_in[19];
    const float* lb  = (const float*)d_in[20];
    const float* bw  = (const float*)d_in[21];
    const float* aw  = (const float*)d_in[22];
    const float* ab  = (const float*)d_in[23];

    float* ws    = (float*)d_ws;
    float* r256  = ws;                    // 786432
    float* f1    = r256 + 786432;         // 1048576
    float* f2    = f1 + 1048576;          // 524288
    float* f3    = f2 + 524288;           // 262144
    float* f4    = f3 + 262144;           // 131072
    float* codes = f4 + 131072;           // 2048
    float* wt    = codes + 2048;          // 12
    float* vert  = wt + 12;               // 396
    float* luts4 = vert + 396;            // 4*35937*4 (16B aligned: offset 2754968 % 4 == 0)

    float* outs  = (float*)d_out;
    float* out_w = outs + (size_t)BATCH * 3 * HW_IMG;  // 12582912
    float* out_v = out_w + 12;

    k_resize<<<3072, 256, 0, stream>>>(lq, r256);
    k_conv<3, 16, 128, 128, 64, true><<<BATCH * 16, 256, 0, stream>>>(r256, w1, b1, g1, be1, f1);
    k_conv<16, 32, 64, 64, 16, true><<<BATCH * 32, 256, 0, stream>>>(f1, w2, b2, g2, be2, f2);
    k_conv<32, 64, 32, 32, 4, true><<<BATCH * 64, 256, 0, stream>>>(f2, w3, b3, g3, be3, f3);
    k_conv<64, 128, 16, 16, 1, true><<<BATCH * 128, 256, 0, stream>>>(f3, w4, b4, g4, be4, f4);
    k_conv5_pool<<<BATCH * 128, 64, 0, stream>>>(f4, w5, b5, codes);
    k_head<<<13, 64, 0, stream>>>(codes, lw, lb, aw, ab, wt, vert, out_w, out_v);
    k_lutgen<<<(BATCH * LUT_D3 + 255) / 256, 256, 0, stream>>>(bw, wt, luts4);
    k_transform<<<BATCH * 1024, 256, 0, stream>>>(lq, luts4, vert, outs);
}

// Round 2
// 567.400 us; speedup vs baseline: 1.7856x; 1.7856x over previous
//
#include <hip/hip_runtime.h>
#include <math.h>

#define LUT_D 33
#define LUT_D3 35937   // 33^3
#define NEG 0.2f
#define BATCH 4
#define HW_IMG 1048576 // 1024*1024

// ---------------- resize 1024 -> 256 (half-pixel bilinear, scale 4 => frac=0.5) -------------
__global__ void k_resize(const float* __restrict__ lq, float* __restrict__ out) {
    int gid = blockIdx.x * 256 + threadIdx.x;     // over 4*3*256*256 = 786432
    if (gid >= BATCH * 3 * 256 * 256) return;
    int x  = gid & 255;
    int y  = (gid >> 8) & 255;
    int pc = gid >> 16;                            // b*3 + c
    const float* in = lq + (size_t)pc * HW_IMG;
    const float* p0 = in + (4 * y + 1) * 1024 + (4 * x + 1);
    out[gid] = 0.25f * (p0[0] + p0[1] + p0[1024] + p0[1025]);
}

// ---------------- tiled conv3x3 s2 p1 + LeakyReLU, fused input-InstanceNorm -----------------
// block = (b, 8x8 output tile, 16-oc group); 256 threads = 64 px * 4 oc-lanes (4 oc each).
// Input staged in LDS in <=32-ic chunks, 17x17 halo tile padded to 18 cols.
// If NORM_IN: input x is normalized on the fly using stats_in (sum, sumsq) + gamma/beta of
// the PREVIOUS layer (zero padding applied after norm, matching reference).
// If STATS_OUT: per-oc sums of activated outputs are atomically accumulated for this layer.
template<int IC, int OC, int OH, int OW, bool NORM_IN, bool STATS_OUT, bool W_LDS>
__global__ void __launch_bounds__(256) k_conv_t(
    const float* __restrict__ in, const float* __restrict__ stats_in,
    const float* __restrict__ g_prev, const float* __restrict__ be_prev,
    const float* __restrict__ w, const float* __restrict__ bias,
    float* __restrict__ out, float* __restrict__ stats_out) {
    constexpr int IH = OH * 2, IW = OW * 2;
    constexpr int ICB = (IC < 32) ? IC : 32;       // ic chunk
    constexpr int CHF = ICB * 306;                 // 17 rows * 18 cols per ic
    constexpr int NTX = OW / 8, NTY = OH / 8, NOCG = OC / 16;

    __shared__ float sIn[CHF];
    __shared__ float swl[W_LDS ? 16 * IC * 9 : 1];

    int id = blockIdx.x;
    int ocg = id % NOCG; id /= NOCG;
    int tx  = id % NTX;  id /= NTX;
    int ty  = id % NTY;  id /= NTY;
    int b   = id;

    int t    = threadIdx.x;
    int lane = t >> 6;          // 0..3
    int px   = t & 63;
    int py   = px >> 3, pxx = px & 7;
    int oc0  = ocg * 16 + lane * 4;

    if (W_LDS) {
        for (int i = t; i < 16 * IC * 9; i += 256) swl[i] = w[(size_t)(ocg * 16) * IC * 9 + i];
    }

    float acc[4];
    #pragma unroll
    for (int j = 0; j < 4; j++) acc[j] = bias[oc0 + j];

    int oy = ty * 8 + py, ox = tx * 8 + pxx;
    int iy0 = ty * 16 - 1, ix0 = tx * 16 - 1;
    const float invN = 1.f / (float)(IH * IW);

    for (int icc = 0; icc < IC; icc += ICB) {
        __syncthreads();
        for (int idx = t; idx < CHF; idx += 256) {
            int ic  = icc + idx / 306;
            int r   = idx % 306;
            int row = r / 18, col = r % 18;
            int iy = iy0 + row, ix = ix0 + col;
            float v = 0.f;
            if (col < 17 && iy >= 0 && iy < IH && ix >= 0 && ix < IW) {
                v = in[((size_t)(b * IC + ic)) * (IH * IW) + iy * IW + ix];
                if (NORM_IN) {
                    float a1 = stats_in[(b * IC + ic) * 2];
                    float a2 = stats_in[(b * IC + ic) * 2 + 1];
                    float m   = a1 * invN;
                    float var = a2 * invN - m * m;
                    float sc  = g_prev[ic] * rsqrtf(var + 1e-5f);
                    v = (v - m) * sc + be_prev[ic];
                }
            }
            sIn[idx] = v;
        }
        __syncthreads();
        for (int i2 = 0; i2 < ICB; i2++) {
            const float* tp = sIn + i2 * 306 + py * 36 + pxx * 2;
            float x0 = tp[0],  x1 = tp[1],  x2 = tp[2];
            float x3 = tp[18], x4 = tp[19], x5 = tp[20];
            float x6 = tp[36], x7 = tp[37], x8 = tp[38];
            #pragma unroll
            for (int j = 0; j < 4; j++) {
                const float* wp = W_LDS ? (swl + ((size_t)(lane * 4 + j) * IC + (icc + i2)) * 9)
                                        : (w + ((size_t)(oc0 + j) * IC + (icc + i2)) * 9);
                acc[j] = fmaf(x0, wp[0], acc[j]);
                acc[j] = fmaf(x1, wp[1], acc[j]);
                acc[j] = fmaf(x2, wp[2], acc[j]);
                acc[j] = fmaf(x3, wp[3], acc[j]);
                acc[j] = fmaf(x4, wp[4], acc[j]);
                acc[j] = fmaf(x5, wp[5], acc[j]);
                acc[j] = fmaf(x6, wp[6], acc[j]);
                acc[j] = fmaf(x7, wp[7], acc[j]);
                acc[j] = fmaf(x8, wp[8], acc[j]);
            }
        }
    }

    #pragma unroll
    for (int j = 0; j < 4; j++) {
        float a = acc[j];
        a = a >= 0.f ? a : NEG * a;
        out[((size_t)(b * OC + oc0 + j) * OH + oy) * OW + ox] = a;
        if (STATS_OUT) {
            float s1 = a, s2 = a * a;
            for (int off = 32; off > 0; off >>= 1) {
                s1 += __shfl_down(s1, off, 64);
                s2 += __shfl_down(s2, off, 64);
            }
            if (px == 0) {
                atomicAdd(&stats_out[(b * OC + oc0 + j) * 2], s1);
                atomicAdd(&stats_out[(b * OC + oc0 + j) * 2 + 1], s2);
            }
        }
    }
}

// ---------------- AdaptiveAvgPool2d(2) on [4,128,8,8] -> codes [4,512] ---------------------
__global__ void k_pool(const float* __restrict__ f5, float* __restrict__ codes) {
    int c = blockIdx.x * 256 + threadIdx.x;   // 2048
    if (c >= 2048) return;
    int b = c >> 9;
    int rest = c & 511;
    int oc = rest >> 2, q = rest & 3;
    int py = (q >> 1) * 4, px = (q & 1) * 4;
    const float* p = f5 + ((size_t)(b * 128 + oc)) * 64;
    float s = 0.f;
    #pragma unroll
    for (int dy = 0; dy < 4; dy++)
        #pragma unroll
        for (int dx = 0; dx < 4; dx++)
            s += p[(py + dy) * 8 + px + dx];
    codes[c] = s * (1.f / 16.f);
}

// ---------------- heads: weights = codes@lw.T+lb ; vertices = pad(cumsum(softmax(...))) ----
__global__ void k_head(const float* __restrict__ codes, const float* __restrict__ lw,
                       const float* __restrict__ lb, const float* __restrict__ aw,
                       const float* __restrict__ ab, float* __restrict__ wt,
                       float* __restrict__ vert, float* __restrict__ out_w,
                       float* __restrict__ out_v) {
    int blk = blockIdx.x;
    int t = threadIdx.x;  // 64 threads
    if (blk == 12) {
        if (t < 12) {
            int b = t / 3, j = t % 3;
            const float* c = codes + b * 512;
            const float* l = lw + j * 512;
            float s = lb[j];
            for (int k = 0; k < 512; k++) s += c[k] * l[k];
            wt[t] = s;
            out_w[t] = s;
        }
        return;
    }
    int b = blk / 3, ch = blk % 3;
    __shared__ float y[32];
    if (t < 32) {
        const float* c = codes + b * 512;
        const float* a = aw + (size_t)(ch * 32 + t) * 512;
        float s = ab[ch * 32 + t];
        for (int k = 0; k < 512; k++) s += c[k] * a[k];
        y[t] = s;
    }
    __syncthreads();
    if (t == 0) {
        float mx = y[0];
        for (int m = 1; m < 32; m++) mx = fmaxf(mx, y[m]);
        float e[32];
        float sum = 0.f;
        for (int m = 0; m < 32; m++) { e[m] = expf(y[m] - mx); sum += e[m]; }
        float inv = 1.f / sum;
        float cum = 0.f;
        float* vb = vert + (b * 3 + ch) * 33;
        float* ob = out_v + (b * 3 + ch) * 33;
        vb[0] = 0.f; ob[0] = 0.f;
        for (int m = 0; m < 32; m++) { cum += e[m] * inv; vb[m + 1] = cum; ob[m + 1] = cum; }
    }
}

// ---------------- LUT generation: luts[b] = bw @ wt[b], relayout to [D][D][D] x float4 -----
__global__ void k_lutgen(const float* __restrict__ bw, const float* __restrict__ wt,
                         float* __restrict__ luts4) {
    int gid = blockIdx.x * 256 + threadIdx.x;     // over 4*35937
    if (gid >= BATCH * LUT_D3) return;
    int b = gid / LUT_D3;
    int cell = gid - b * LUT_D3;
    float w0 = wt[b * 3], w1 = wt[b * 3 + 1], w2 = wt[b * 3 + 2];
    const float* r0 = bw + (size_t)(0 * LUT_D3 + cell) * 3;
    const float* r1 = bw + (size_t)(1 * LUT_D3 + cell) * 3;
    const float* r2 = bw + (size_t)(2 * LUT_D3 + cell) * 3;
    float4 o;
    o.x = r0[0] * w0 + r0[1] * w1 + r0[2] * w2;
    o.y = r1[0] * w0 + r1[1] * w1 + r1[2] * w2;
    o.z = r2[0] * w0 + r2[1] * w1 + r2[2] * w2;
    o.w = 0.f;
    ((float4*)luts4)[gid] = o;
}

// ---------------- per-pixel searchsorted + trilinear LUT sample ----------------------------
__device__ __forceinline__ void search1(const float* __restrict__ sv, int ch, float x,
                                        int& i0, float& f) {
    const float* v = sv + ch * LUT_D;
    int lo = 0, hi = LUT_D;
    while (lo < hi) { int mid = (lo + hi) >> 1; if (v[mid] <= x) lo = mid + 1; else hi = mid; }
    int idx = lo < 1 ? 1 : (lo > LUT_D - 1 ? LUT_D - 1 : lo);
    float vl = v[idx - 1], vh = v[idx];
    float fr = (x - vl) / (vh - vl + 1e-8f);
    float coord = (float)(idx - 1) + fr;
    coord = fminf(fmaxf(coord, 0.f), (float)(LUT_D - 1));
    i0 = (int)floorf(coord);
    if (i0 > LUT_D - 2) i0 = LUT_D - 2;
    f = coord - (float)i0;
}

__global__ void __launch_bounds__(256) k_transform(const float* __restrict__ lq,
                                                   const float* __restrict__ luts4,
                                                   const float* __restrict__ vert,
                                                   float* __restrict__ out) {
    int bimg = blockIdx.x >> 10;                  // 1024 blocks per image
    int blk  = blockIdx.x & 1023;
    __shared__ float sv[3 * LUT_D];
    if (threadIdx.x < 3 * LUT_D) sv[threadIdx.x] = vert[bimg * 3 * LUT_D + threadIdx.x];
    __syncthreads();
    int p0 = blk * 1024 + threadIdx.x * 4;        // 4 px per thread
    const float* lr = lq + (size_t)bimg * 3 * HW_IMG + p0;
    float4 r4 = *(const float4*)(lr);
    float4 g4 = *(const float4*)(lr + HW_IMG);
    float4 b4 = *(const float4*)(lr + 2 * HW_IMG);
    const float4* L = (const float4*)(luts4 + (size_t)bimg * LUT_D3 * 4);
    float rr[4] = {r4.x, r4.y, r4.z, r4.w};
    float gg[4] = {g4.x, g4.y, g4.z, g4.w};
    float bb[4] = {b4.x, b4.y, b4.z, b4.w};
    float ro[4], go[4], bo[4];
    #pragma unroll
    for (int i = 0; i < 4; i++) {
        int i0, j0, k0; float fr, fg, fb;
        search1(sv, 0, rr[i], i0, fr);
        search1(sv, 1, gg[i], j0, fg);
        search1(sv, 2, bb[i], k0, fb);
        int base = (i0 * LUT_D + j0) * LUT_D + k0;
        float4 q000 = L[base],        q001 = L[base + 1];
        float4 q010 = L[base + 33],   q011 = L[base + 34];
        float4 q100 = L[base + 1089], q101 = L[base + 1090];
        float4 q110 = L[base + 1122], q111 = L[base + 1123];
        float w000 = (1.f - fr) * (1.f - fg) * (1.f - fb), w001 = (1.f - fr) * (1.f - fg) * fb;
        float w010 = (1.f - fr) * fg * (1.f - fb),         w011 = (1.f - fr) * fg * fb;
        float w100 = fr * (1.f - fg) * (1.f - fb),         w101 = fr * (1.f - fg) * fb;
        float w110 = fr * fg * (1.f - fb),                 w111 = fr * fg * fb;
        float rx = q000.x*w000 + q001.x*w001 + q010.x*w010 + q011.x*w011
                 + q100.x*w100 + q101.x*w101 + q110.x*w110 + q111.x*w111;
        float ry = q000.y*w000 + q001.y*w001 + q010.y*w010 + q011.y*w011
                 + q100.y*w100 + q101.y*w101 + q110.y*w110 + q111.y*w111;
        float rz = q000.z*w000 + q001.z*w001 + q010.z*w010 + q011.z*w011
                 + q100.z*w100 + q101.z*w101 + q110.z*w110 + q111.z*w111;
        ro[i] = fminf(fmaxf(rx, 0.f), 1.f);
        go[i] = fminf(fmaxf(ry, 0.f), 1.f);
        bo[i] = fminf(fmaxf(rz, 0.f), 1.f);
    }
    float* op = out + (size_t)bimg * 3 * HW_IMG + p0;
    float4 o0 = {ro[0], ro[1], ro[2], ro[3]};
    float4 o1 = {go[0], go[1], go[2], go[3]};
    float4 o2 = {bo[0], bo[1], bo[2], bo[3]};
    *(float4*)(op) = o0;
    *(float4*)(op + HW_IMG) = o1;
    *(float4*)(op + 2 * HW_IMG) = o2;
}

extern "C" void kernel_launch(void* const* d_in, const int* in_sizes, int n_in,
                              void* d_out, int out_size, void* d_ws, size_t ws_size,
                              hipStream_t stream) {
    const float* lq  = (const float*)d_in[0];
    const float* w1  = (const float*)d_in[1];
    const float* b1  = (const float*)d_in[2];
    const float* g1  = (const float*)d_in[3];
    const float* be1 = (const float*)d_in[4];
    const float* w2  = (const float*)d_in[5];
    const float* b2  = (const float*)d_in[6];
    const float* g2  = (const float*)d_in[7];
    const float* be2 = (const float*)d_in[8];
    const float* w3  = (const float*)d_in[9];
    const float* b3  = (const float*)d_in[10];
    const float* g3  = (const float*)d_in[11];
    const float* be3 = (const float*)d_in[12];
    const float* w4  = (const float*)d_in[13];
    const float* b4  = (const float*)d_in[14];
    const float* g4  = (const float*)d_in[15];
    const float* be4 = (const float*)d_in[16];
    const float* w5  = (const float*)d_in[17];
    const float* b5  = (const float*)d_in[18];
    const float* lw  = (const float*)d_in[19];
    const float* lb  = (const float*)d_in[20];
    const float* bw  = (const float*)d_in[21];
    const float* aw  = (const float*)d_in[22];
    const float* ab  = (const float*)d_in[23];

    float* ws     = (float*)d_ws;
    float* r256   = ws;                    // 786432
    float* f1     = r256 + 786432;         // 1048576
    float* f2     = f1 + 1048576;          // 524288
    float* f3     = f2 + 524288;           // 262144
    float* f4     = f3 + 262144;           // 131072
    float* f5     = f4 + 131072;           // 32768 (4x128x8x8)
    float* codes  = f5 + 32768;            // 2048
    float* wt     = codes + 2048;          // 12
    float* vert   = wt + 12;               // 396
    float* stats  = vert + 396;            // 1920 total
    float* stats1 = stats;                 // 4*16*2  = 128
    float* stats2 = stats1 + 128;          // 4*32*2  = 256
    float* stats3 = stats2 + 256;          // 4*64*2  = 512
    float* stats4 = stats3 + 512;          // 4*128*2 = 1024
    float* luts4  = stats + 1920;          // 4*35937*4; byte offset 2789656*4 % 16 == 0

    float* outs  = (float*)d_out;
    float* out_w = outs + (size_t)BATCH * 3 * HW_IMG;  // 12582912
    float* out_v = out_w + 12;

    hipMemsetAsync(stats, 0, 1920 * sizeof(float), stream);
    k_resize<<<3072, 256, 0, stream>>>(lq, r256);
    // S1: in [4,3,256,256] -> f1 [4,16,128,128]; grid 4*16*16*1 = 1024
    k_conv_t<3, 16, 128, 128, false, true, true><<<1024, 256, 0, stream>>>(
        r256, nullptr, nullptr, nullptr, w1, b1, f1, stats1);
    // S2: -> f2 [4,32,64,64]; grid 4*8*8*2 = 512
    k_conv_t<16, 32, 64, 64, true, true, true><<<512, 256, 0, stream>>>(
        f1, stats1, g1, be1, w2, b2, f2, stats2);
    // S3: -> f3 [4,64,32,32]; grid 4*4*4*4 = 256
    k_conv_t<32, 64, 32, 32, true, true, true><<<256, 256, 0, stream>>>(
        f2, stats2, g2, be2, w3, b3, f3, stats3);
    // S4: -> f4 [4,128,16,16]; grid 4*2*2*8 = 128
    k_conv_t<64, 128, 16, 16, true, true, false><<<128, 256, 0, stream>>>(
        f3, stats3, g3, be3, w4, b4, f4, stats4);
    // S5: -> f5 [4,128,8,8]; grid 4*1*1*8 = 32 (no IN after; input normed with stats4)
    k_conv_t<128, 128, 8, 8, true, false, false><<<32, 256, 0, stream>>>(
        f4, stats4, g4, be4, w5, b5, f5, nullptr);
    k_pool<<<8, 256, 0, stream>>>(f5, codes);
    k_head<<<13, 64, 0, stream>>>(codes, lw, lb, aw, ab, wt, vert, out_w, out_v);
    k_lutgen<<<(BATCH * LUT_D3 + 255) / 256, 256, 0, stream>>>(bw, wt, luts4);
    k_transform<<<BATCH * 1024, 256, 0, stream>>>(lq, luts4, vert, outs);
}

// Round 3
// 448.916 us; speedup vs baseline: 2.2569x; 1.2639x over previous
//
#include <hip/hip_runtime.h>
#include <math.h>

#define LUT_D 33
#define LUT_D3 35937   // 33^3
#define NEG 0.2f
#define BATCH 4
#define HW_IMG 1048576 // 1024*1024

// ---------------- resize 1024 -> 256 (half-pixel bilinear, scale 4 => frac=0.5) -------------
__global__ void k_resize(const float* __restrict__ lq, float* __restrict__ out) {
    int gid = blockIdx.x * 256 + threadIdx.x;     // over 4*3*256*256 = 786432
    if (gid >= BATCH * 3 * 256 * 256) return;
    int x  = gid & 255;
    int y  = (gid >> 8) & 255;
    int pc = gid >> 16;                            // b*3 + c
    const float* in = lq + (size_t)pc * HW_IMG;
    const float* p0 = in + (4 * y + 1) * 1024 + (4 * x + 1);
    out[gid] = 0.25f * (p0[0] + p0[1] + p0[1024] + p0[1025]);
}

// ---------------- tiled conv3x3 s2 p1 + LeakyReLU, fused input-InstanceNorm -----------------
// block = (b, 8x8 output tile, 16-oc group); 256 threads = 64 px * 4 oc-lanes (4 oc each).
// Input staged in LDS in <=32-ic chunks, 17x17 halo tile padded to 18 cols.
// If NORM_IN: input x is normalized on the fly using stats_in (sum, sumsq) + gamma/beta of
// the PREVIOUS layer (zero padding applied after norm, matching reference).
// If STATS_OUT: per-(oc,tile) partial sums written to `part` (no atomics; k_stats reduces).
template<int IC, int OC, int OH, int OW, bool NORM_IN, bool STATS_OUT, bool W_LDS>
__global__ void __launch_bounds__(256) k_conv_t(
    const float* __restrict__ in, const float* __restrict__ stats_in,
    const float* __restrict__ g_prev, const float* __restrict__ be_prev,
    const float* __restrict__ w, const float* __restrict__ bias,
    float* __restrict__ out, float* __restrict__ part) {
    constexpr int IH = OH * 2, IW = OW * 2;
    constexpr int ICB = (IC < 32) ? IC : 32;       // ic chunk
    constexpr int CHF = ICB * 306;                 // 17 rows * 18 cols per ic
    constexpr int NTX = OW / 8, NTY = OH / 8, NOCG = OC / 16;
    constexpr int NT = NTX * NTY;

    __shared__ float sIn[CHF];
    __shared__ float swl[W_LDS ? 16 * IC * 9 : 1];

    int id = blockIdx.x;
    int ocg = id % NOCG; id /= NOCG;
    int tx  = id % NTX;  id /= NTX;
    int ty  = id % NTY;  id /= NTY;
    int b   = id;

    int t    = threadIdx.x;
    int lane = t >> 6;          // 0..3
    int px   = t & 63;
    int py   = px >> 3, pxx = px & 7;
    int oc0  = ocg * 16 + lane * 4;

    if (W_LDS) {
        for (int i = t; i < 16 * IC * 9; i += 256) swl[i] = w[(size_t)(ocg * 16) * IC * 9 + i];
    }

    float acc[4];
    #pragma unroll
    for (int j = 0; j < 4; j++) acc[j] = bias[oc0 + j];

    int oy = ty * 8 + py, ox = tx * 8 + pxx;
    int iy0 = ty * 16 - 1, ix0 = tx * 16 - 1;
    const float invN = 1.f / (float)(IH * IW);

    for (int icc = 0; icc < IC; icc += ICB) {
        __syncthreads();
        for (int idx = t; idx < CHF; idx += 256) {
            int ic  = icc + idx / 306;
            int r   = idx % 306;
            int row = r / 18, col = r % 18;
            int iy = iy0 + row, ix = ix0 + col;
            float v = 0.f;
            if (col < 17 && iy >= 0 && iy < IH && ix >= 0 && ix < IW) {
                v = in[((size_t)(b * IC + ic)) * (IH * IW) + iy * IW + ix];
                if (NORM_IN) {
                    float a1 = stats_in[(b * IC + ic) * 2];
                    float a2 = stats_in[(b * IC + ic) * 2 + 1];
                    float m   = a1 * invN;
                    float var = a2 * invN - m * m;
                    float sc  = g_prev[ic] * rsqrtf(var + 1e-5f);
                    v = (v - m) * sc + be_prev[ic];
                }
            }
            sIn[idx] = v;
        }
        __syncthreads();
        for (int i2 = 0; i2 < ICB; i2++) {
            const float* tp = sIn + i2 * 306 + py * 36 + pxx * 2;
            float x0 = tp[0],  x1 = tp[1],  x2 = tp[2];
            float x3 = tp[18], x4 = tp[19], x5 = tp[20];
            float x6 = tp[36], x7 = tp[37], x8 = tp[38];
            #pragma unroll
            for (int j = 0; j < 4; j++) {
                const float* wp = W_LDS ? (swl + ((size_t)(lane * 4 + j) * IC + (icc + i2)) * 9)
                                        : (w + ((size_t)(oc0 + j) * IC + (icc + i2)) * 9);
                acc[j] = fmaf(x0, wp[0], acc[j]);
                acc[j] = fmaf(x1, wp[1], acc[j]);
                acc[j] = fmaf(x2, wp[2], acc[j]);
                acc[j] = fmaf(x3, wp[3], acc[j]);
                acc[j] = fmaf(x4, wp[4], acc[j]);
                acc[j] = fmaf(x5, wp[5], acc[j]);
                acc[j] = fmaf(x6, wp[6], acc[j]);
                acc[j] = fmaf(x7, wp[7], acc[j]);
                acc[j] = fmaf(x8, wp[8], acc[j]);
            }
        }
    }

    int tile = ty * NTX + tx;
    #pragma unroll
    for (int j = 0; j < 4; j++) {
        float a = acc[j];
        a = a >= 0.f ? a : NEG * a;
        out[((size_t)(b * OC + oc0 + j) * OH + oy) * OW + ox] = a;
        if (STATS_OUT) {
            float s1 = a, s2 = a * a;
            for (int off = 32; off > 0; off >>= 1) {
                s1 += __shfl_down(s1, off, 64);
                s2 += __shfl_down(s2, off, 64);
            }
            if (px == 0) {
                size_t pi = ((size_t)(b * OC + oc0 + j) * NT + tile) * 2;
                part[pi]     = s1;
                part[pi + 1] = s2;
            }
        }
    }
}

// ---------------- reduce per-tile partials -> per-(b,oc) stats (sum, sumsq) ----------------
template<int NT>
__global__ void k_stats(const float* __restrict__ part, float* __restrict__ stats) {
    int bc = blockIdx.x;
    int t  = threadIdx.x;  // 64
    float s1 = 0.f, s2 = 0.f;
    for (int i = t; i < NT; i += 64) {
        s1 += part[((size_t)bc * NT + i) * 2];
        s2 += part[((size_t)bc * NT + i) * 2 + 1];
    }
    #pragma unroll
    for (int off = 32; off > 0; off >>= 1) {
        s1 += __shfl_down(s1, off, 64);
        s2 += __shfl_down(s2, off, 64);
    }
    if (t == 0) { stats[bc * 2] = s1; stats[bc * 2 + 1] = s2; }
}

// ---------------- AdaptiveAvgPool2d(2) on [4,128,8,8] -> codes [4,512] ---------------------
__global__ void k_pool(const float* __restrict__ f5, float* __restrict__ codes) {
    int c = blockIdx.x * 256 + threadIdx.x;   // 2048
    if (c >= 2048) return;
    int b = c >> 9;
    int rest = c & 511;
    int oc = rest >> 2, q = rest & 3;
    int py = (q >> 1) * 4, px = (q & 1) * 4;
    const float* p = f5 + ((size_t)(b * 128 + oc)) * 64;
    float s = 0.f;
    #pragma unroll
    for (int dy = 0; dy < 4; dy++)
        #pragma unroll
        for (int dx = 0; dx < 4; dx++)
            s += p[(py + dy) * 8 + px + dx];
    codes[c] = s * (1.f / 16.f);
}

// ---------------- heads: weights = codes@lw.T+lb ; vertices = pad(cumsum(softmax(...))) ----
__global__ void k_head(const float* __restrict__ codes, const float* __restrict__ lw,
                       const float* __restrict__ lb, const float* __restrict__ aw,
                       const float* __restrict__ ab, float* __restrict__ wt,
                       float* __restrict__ vert, float* __restrict__ out_w,
                       float* __restrict__ out_v) {
    int blk = blockIdx.x;
    int t = threadIdx.x;  // 64 threads
    if (blk == 12) {
        if (t < 12) {
            int b = t / 3, j = t % 3;
            const float* c = codes + b * 512;
            const float* l = lw + j * 512;
            float s = lb[j];
            for (int k = 0; k < 512; k++) s += c[k] * l[k];
            wt[t] = s;
            out_w[t] = s;
        }
        return;
    }
    int b = blk / 3, ch = blk % 3;
    __shared__ float y[32];
    if (t < 32) {
        const float* c = codes + b * 512;
        const float* a = aw + (size_t)(ch * 32 + t) * 512;
        float s = ab[ch * 32 + t];
        for (int k = 0; k < 512; k++) s += c[k] * a[k];
        y[t] = s;
    }
    __syncthreads();
    if (t == 0) {
        float mx = y[0];
        for (int m = 1; m < 32; m++) mx = fmaxf(mx, y[m]);
        float e[32];
        float sum = 0.f;
        for (int m = 0; m < 32; m++) { e[m] = expf(y[m] - mx); sum += e[m]; }
        float inv = 1.f / sum;
        float cum = 0.f;
        float* vb = vert + (b * 3 + ch) * 33;
        float* ob = out_v + (b * 3 + ch) * 33;
        vb[0] = 0.f; ob[0] = 0.f;
        for (int m = 0; m < 32; m++) { cum += e[m] * inv; vb[m + 1] = cum; ob[m + 1] = cum; }
    }
}

// ---------------- LUT generation: luts[b] = bw @ wt[b], relayout to [D][D][D] x float4 -----
__global__ void k_lutgen(const float* __restrict__ bw, const float* __restrict__ wt,
                         float* __restrict__ luts4) {
    int gid = blockIdx.x * 256 + threadIdx.x;     // over 4*35937
    if (gid >= BATCH * LUT_D3) return;
    int b = gid / LUT_D3;
    int cell = gid - b * LUT_D3;
    float w0 = wt[b * 3], w1 = wt[b * 3 + 1], w2 = wt[b * 3 + 2];
    const float* r0 = bw + (size_t)(0 * LUT_D3 + cell) * 3;
    const float* r1 = bw + (size_t)(1 * LUT_D3 + cell) * 3;
    const float* r2 = bw + (size_t)(2 * LUT_D3 + cell) * 3;
    float4 o;
    o.x = r0[0] * w0 + r0[1] * w1 + r0[2] * w2;
    o.y = r1[0] * w0 + r1[1] * w1 + r1[2] * w2;
    o.z = r2[0] * w0 + r2[1] * w1 + r2[2] * w2;
    o.w = 0.f;
    ((float4*)luts4)[gid] = o;
}

// ---------------- per-pixel searchsorted + trilinear LUT sample ----------------------------
__device__ __forceinline__ void search1(const float* __restrict__ sv, int ch, float x,
                                        int& i0, float& f) {
    const float* v = sv + ch * LUT_D;
    int lo = 0, hi = LUT_D;
    while (lo < hi) { int mid = (lo + hi) >> 1; if (v[mid] <= x) lo = mid + 1; else hi = mid; }
    int idx = lo < 1 ? 1 : (lo > LUT_D - 1 ? LUT_D - 1 : lo);
    float vl = v[idx - 1], vh = v[idx];
    float fr = (x - vl) / (vh - vl + 1e-8f);
    float coord = (float)(idx - 1) + fr;
    coord = fminf(fmaxf(coord, 0.f), (float)(LUT_D - 1));
    i0 = (int)floorf(coord);
    if (i0 > LUT_D - 2) i0 = LUT_D - 2;
    f = coord - (float)i0;
}

__global__ void __launch_bounds__(256) k_transform(const float* __restrict__ lq,
                                                   const float* __restrict__ luts4,
                                                   const float* __restrict__ vert,
                                                   float* __restrict__ out) {
    int bimg = blockIdx.x >> 10;                  // 1024 blocks per image
    int blk  = blockIdx.x & 1023;
    __shared__ float sv[3 * LUT_D];
    if (threadIdx.x < 3 * LUT_D) sv[threadIdx.x] = vert[bimg * 3 * LUT_D + threadIdx.x];
    __syncthreads();
    int p0 = blk * 1024 + threadIdx.x * 4;        // 4 px per thread
    const float* lr = lq + (size_t)bimg * 3 * HW_IMG + p0;
    float4 r4 = *(const float4*)(lr);
    float4 g4 = *(const float4*)(lr + HW_IMG);
    float4 b4 = *(const float4*)(lr + 2 * HW_IMG);
    const float4* L = (const float4*)(luts4 + (size_t)bimg * LUT_D3 * 4);
    float rr[4] = {r4.x, r4.y, r4.z, r4.w};
    float gg[4] = {g4.x, g4.y, g4.z, g4.w};
    float bb[4] = {b4.x, b4.y, b4.z, b4.w};
    float ro[4], go[4], bo[4];
    #pragma unroll
    for (int i = 0; i < 4; i++) {
        int i0, j0, k0; float fr, fg, fb;
        search1(sv, 0, rr[i], i0, fr);
        search1(sv, 1, gg[i], j0, fg);
        search1(sv, 2, bb[i], k0, fb);
        int base = (i0 * LUT_D + j0) * LUT_D + k0;
        float4 q000 = L[base],        q001 = L[base + 1];
        float4 q010 = L[base + 33],   q011 = L[base + 34];
        float4 q100 = L[base + 1089], q101 = L[base + 1090];
        float4 q110 = L[base + 1122], q111 = L[base + 1123];
        float w000 = (1.f - fr) * (1.f - fg) * (1.f - fb), w001 = (1.f - fr) * (1.f - fg) * fb;
        float w010 = (1.f - fr) * fg * (1.f - fb),         w011 = (1.f - fr) * fg * fb;
        float w100 = fr * (1.f - fg) * (1.f - fb),         w101 = fr * (1.f - fg) * fb;
        float w110 = fr * fg * (1.f - fb),                 w111 = fr * fg * fb;
        float rx = q000.x*w000 + q001.x*w001 + q010.x*w010 + q011.x*w011
                 + q100.x*w100 + q101.x*w101 + q110.x*w110 + q111.x*w111;
        float ry = q000.y*w000 + q001.y*w001 + q010.y*w010 + q011.y*w011
                 + q100.y*w100 + q101.y*w101 + q110.y*w110 + q111.y*w111;
        float rz = q000.z*w000 + q001.z*w001 + q010.z*w010 + q011.z*w011
                 + q100.z*w100 + q101.z*w101 + q110.z*w110 + q111.z*w111;
        ro[i] = fminf(fmaxf(rx, 0.f), 1.f);
        go[i] = fminf(fmaxf(ry, 0.f), 1.f);
        bo[i] = fminf(fmaxf(rz, 0.f), 1.f);
    }
    float* op = out + (size_t)bimg * 3 * HW_IMG + p0;
    float4 o0 = {ro[0], ro[1], ro[2], ro[3]};
    float4 o1 = {go[0], go[1], go[2], go[3]};
    float4 o2 = {bo[0], bo[1], bo[2], bo[3]};
    *(float4*)(op) = o0;
    *(float4*)(op + HW_IMG) = o1;
    *(float4*)(op + 2 * HW_IMG) = o2;
}

extern "C" void kernel_launch(void* const* d_in, const int* in_sizes, int n_in,
                              void* d_out, int out_size, void* d_ws, size_t ws_size,
                              hipStream_t stream) {
    const float* lq  = (const float*)d_in[0];
    const float* w1  = (const float*)d_in[1];
    const float* b1  = (const float*)d_in[2];
    const float* g1  = (const float*)d_in[3];
    const float* be1 = (const float*)d_in[4];
    const float* w2  = (const float*)d_in[5];
    const float* b2  = (const float*)d_in[6];
    const float* g2  = (const float*)d_in[7];
    const float* be2 = (const float*)d_in[8];
    const float* w3  = (const float*)d_in[9];
    const float* b3  = (const float*)d_in[10];
    const float* g3  = (const float*)d_in[11];
    const float* be3 = (const float*)d_in[12];
    const float* w4  = (const float*)d_in[13];
    const float* b4  = (const float*)d_in[14];
    const float* g4  = (const float*)d_in[15];
    const float* be4 = (const float*)d_in[16];
    const float* w5  = (const float*)d_in[17];
    const float* b5  = (const float*)d_in[18];
    const float* lw  = (const float*)d_in[19];
    const float* lb  = (const float*)d_in[20];
    const float* bw  = (const float*)d_in[21];
    const float* aw  = (const float*)d_in[22];
    const float* ab  = (const float*)d_in[23];

    float* ws     = (float*)d_ws;
    float* r256   = ws;                    // 786432
    float* f1     = r256 + 786432;         // 1048576
    float* f2     = f1 + 1048576;          // 524288
    float* f3     = f2 + 524288;           // 262144
    float* f4     = f3 + 262144;           // 131072
    float* f5     = f4 + 131072;           // 32768 (4x128x8x8)
    float* codes  = f5 + 32768;            // 2048
    float* wt     = codes + 2048;          // 12
    float* vert   = wt + 12;               // 396
    float* stats  = vert + 396;            // 1920 floats of stats
    float* stats1 = stats;                 // 4*16*2  = 128
    float* stats2 = stats1 + 128;          // 4*32*2  = 256
    float* stats3 = stats2 + 256;          // 4*64*2  = 512
    float* stats4 = stats3 + 512;          // 4*128*2 = 1024
    float* part1  = stats + 1920;          // 64*256*2  = 32768
    float* part2  = part1 + 32768;         // 128*64*2  = 16384
    float* part3  = part2 + 16384;         // 256*16*2  = 8192
    float* part4  = part3 + 8192;          // 512*4*2   = 4096
    float* luts4  = part4 + 4096;          // 4*35937*4; offset 2851096 % 4 == 0 (16B aligned)

    float* outs  = (float*)d_out;
    float* out_w = outs + (size_t)BATCH * 3 * HW_IMG;  // 12582912
    float* out_v = out_w + 12;

    k_resize<<<3072, 256, 0, stream>>>(lq, r256);
    // S1: in [4,3,256,256] -> f1 [4,16,128,128]; grid 4*16*16*1 = 1024
    k_conv_t<3, 16, 128, 128, false, true, true><<<1024, 256, 0, stream>>>(
        r256, nullptr, nullptr, nullptr, w1, b1, f1, part1);
    k_stats<256><<<64, 64, 0, stream>>>(part1, stats1);
    // S2: -> f2 [4,32,64,64]; grid 4*8*8*2 = 512
    k_conv_t<16, 32, 64, 64, true, true, true><<<512, 256, 0, stream>>>(
        f1, stats1, g1, be1, w2, b2, f2, part2);
    k_stats<64><<<128, 64, 0, stream>>>(part2, stats2);
    // S3: -> f3 [4,64,32,32]; grid 4*4*4*4 = 256
    k_conv_t<32, 64, 32, 32, true, true, true><<<256, 256, 0, stream>>>(
        f2, stats2, g2, be2, w3, b3, f3, part3);
    k_stats<16><<<256, 64, 0, stream>>>(part3, stats3);
    // S4: -> f4 [4,128,16,16]; grid 4*2*2*8 = 128
    k_conv_t<64, 128, 16, 16, true, true, false><<<128, 256, 0, stream>>>(
        f3, stats3, g3, be3, w4, b4, f4, part4);
    k_stats<4><<<512, 64, 0, stream>>>(part4, stats4);
    // S5: -> f5 [4,128,8,8]; grid 4*1*1*8 = 32 (no IN after; input normed with stats4)
    k_conv_t<128, 128, 8, 8, true, false, false><<<32, 256, 0, stream>>>(
        f4, stats4, g4, be4, w5, b5, f5, nullptr);
    k_pool<<<8, 256, 0, stream>>>(f5, codes);
    k_head<<<13, 64, 0, stream>>>(codes, lw, lb, aw, ab, wt, vert, out_w, out_v);
    k_lutgen<<<(BATCH * LUT_D3 + 255) / 256, 256, 0, stream>>>(bw, wt, luts4);
    k_transform<<<BATCH * 1024, 256, 0, stream>>>(lq, luts4, vert, outs);
}

// Round 4
// 448.226 us; speedup vs baseline: 2.2604x; 1.0015x over previous
//
#include <hip/hip_runtime.h>
#include <math.h>

#define LUT_D 33
#define LUT_D3 35937   // 33^3
#define NEG 0.2f
#define BATCH 4
#define HW_IMG 1048576 // 1024*1024

// ---------------- resize 1024 -> 256 (half-pixel bilinear, scale 4 => frac=0.5) -------------
__global__ void k_resize(const float* __restrict__ lq, float* __restrict__ out) {
    int gid = blockIdx.x * 256 + threadIdx.x;     // over 4*3*256*256 = 786432
    if (gid >= BATCH * 3 * 256 * 256) return;
    int x  = gid & 255;
    int y  = (gid >> 8) & 255;
    int pc = gid >> 16;                            // b*3 + c
    const float* in = lq + (size_t)pc * HW_IMG;
    const float* p0 = in + (4 * y + 1) * 1024 + (4 * x + 1);
    out[gid] = 0.25f * (p0[0] + p0[1] + p0[1024] + p0[1025]);
}

// ---------------- tiled conv3x3 s2 p1 + LeakyReLU, fused input-InstanceNorm -----------------
// block = (b, 8x8 output tile, 16-oc group); 256 threads = 64 px * 4 oc-lanes (4 oc each).
// Input staged in LDS in <=32-ic chunks (17x17 halo, 18-col rows); weights for the current
// chunk (16 oc x ICB x 9) also staged in LDS each chunk -> inner loop is LDS-only.
// If NORM_IN: input normalized on the fly from stats_in + prev gamma/beta (zero-pad post-norm).
// If STATS_OUT: per-(oc,tile) partials written plain (k_stats reduces; no atomics).
template<int IC, int OC, int OH, int OW, bool NORM_IN, bool STATS_OUT>
__global__ void __launch_bounds__(256) k_conv_t(
    const float* __restrict__ in, const float* __restrict__ stats_in,
    const float* __restrict__ g_prev, const float* __restrict__ be_prev,
    const float* __restrict__ w, const float* __restrict__ bias,
    float* __restrict__ out, float* __restrict__ part) {
    constexpr int IH = OH * 2, IW = OW * 2;
    constexpr int ICB = (IC < 32) ? IC : 32;       // ic chunk
    constexpr int CHF = ICB * 306;                 // 17 rows * 18 cols per ic
    constexpr int WCH = 16 * ICB * 9;              // per-chunk weights
    constexpr int NTX = OW / 8, NTY = OH / 8, NOCG = OC / 16;
    constexpr int NT = NTX * NTY;

    __shared__ float sIn[CHF];
    __shared__ float swl[WCH];

    int id = blockIdx.x;
    int ocg = id % NOCG; id /= NOCG;
    int tx  = id % NTX;  id /= NTX;
    int ty  = id % NTY;  id /= NTY;
    int b   = id;

    int t    = threadIdx.x;
    int lane = t >> 6;          // 0..3
    int px   = t & 63;
    int py   = px >> 3, pxx = px & 7;
    int oc0  = ocg * 16 + lane * 4;

    float acc[4];
    #pragma unroll
    for (int j = 0; j < 4; j++) acc[j] = bias[oc0 + j];

    int oy = ty * 8 + py, ox = tx * 8 + pxx;
    int iy0 = ty * 16 - 1, ix0 = tx * 16 - 1;
    const float invN = 1.f / (float)(IH * IW);

    for (int icc = 0; icc < IC; icc += ICB) {
        __syncthreads();
        // stage this chunk's weights: layout [oc_local][i2][k]
        for (int i = t; i < WCH; i += 256) {
            int oc_l = i / (ICB * 9);
            int rem  = i % (ICB * 9);
            swl[i] = w[((size_t)(ocg * 16 + oc_l) * IC + icc) * 9 + rem];
        }
        // stage input tile
        for (int idx = t; idx < CHF; idx += 256) {
            int ic  = icc + idx / 306;
            int r   = idx % 306;
            int row = r / 18, col = r % 18;
            int iy = iy0 + row, ix = ix0 + col;
            float v = 0.f;
            if (col < 17 && iy >= 0 && iy < IH && ix >= 0 && ix < IW) {
                v = in[((size_t)(b * IC + ic)) * (IH * IW) + iy * IW + ix];
                if (NORM_IN) {
                    float a1 = stats_in[(b * IC + ic) * 2];
                    float a2 = stats_in[(b * IC + ic) * 2 + 1];
                    float m   = a1 * invN;
                    float var = a2 * invN - m * m;
                    float sc  = g_prev[ic] * rsqrtf(var + 1e-5f);
                    v = (v - m) * sc + be_prev[ic];
                }
            }
            sIn[idx] = v;
        }
        __syncthreads();
        for (int i2 = 0; i2 < ICB; i2++) {
            const float* tp = sIn + i2 * 306 + py * 36 + pxx * 2;
            float x0 = tp[0],  x1 = tp[1],  x2 = tp[2];
            float x3 = tp[18], x4 = tp[19], x5 = tp[20];
            float x6 = tp[36], x7 = tp[37], x8 = tp[38];
            #pragma unroll
            for (int j = 0; j < 4; j++) {
                const float* wp = swl + ((lane * 4 + j) * ICB + i2) * 9;
                acc[j] = fmaf(x0, wp[0], acc[j]);
                acc[j] = fmaf(x1, wp[1], acc[j]);
                acc[j] = fmaf(x2, wp[2], acc[j]);
                acc[j] = fmaf(x3, wp[3], acc[j]);
                acc[j] = fmaf(x4, wp[4], acc[j]);
                acc[j] = fmaf(x5, wp[5], acc[j]);
                acc[j] = fmaf(x6, wp[6], acc[j]);
                acc[j] = fmaf(x7, wp[7], acc[j]);
                acc[j] = fmaf(x8, wp[8], acc[j]);
            }
        }
    }

    int tile = ty * NTX + tx;
    #pragma unroll
    for (int j = 0; j < 4; j++) {
        float a = acc[j];
        a = a >= 0.f ? a : NEG * a;
        out[((size_t)(b * OC + oc0 + j) * OH + oy) * OW + ox] = a;
        if (STATS_OUT) {
            float s1 = a, s2 = a * a;
            for (int off = 32; off > 0; off >>= 1) {
                s1 += __shfl_down(s1, off, 64);
                s2 += __shfl_down(s2, off, 64);
            }
            if (px == 0) {
                size_t pi = ((size_t)(b * OC + oc0 + j) * NT + tile) * 2;
                part[pi]     = s1;
                part[pi + 1] = s2;
            }
        }
    }
}

// ---------------- reduce per-tile partials -> per-(b,oc) stats (sum, sumsq) ----------------
template<int NT>
__global__ void k_stats(const float* __restrict__ part, float* __restrict__ stats) {
    int bc = blockIdx.x;
    int t  = threadIdx.x;  // 64
    float s1 = 0.f, s2 = 0.f;
    for (int i = t; i < NT; i += 64) {
        s1 += part[((size_t)bc * NT + i) * 2];
        s2 += part[((size_t)bc * NT + i) * 2 + 1];
    }
    #pragma unroll
    for (int off = 32; off > 0; off >>= 1) {
        s1 += __shfl_down(s1, off, 64);
        s2 += __shfl_down(s2, off, 64);
    }
    if (t == 0) { stats[bc * 2] = s1; stats[bc * 2 + 1] = s2; }
}

// ---------------- AdaptiveAvgPool2d(2) on [4,128,8,8] -> codes [4,512] ---------------------
__global__ void k_pool(const float* __restrict__ f5, float* __restrict__ codes) {
    int c = blockIdx.x * 256 + threadIdx.x;   // 2048
    if (c >= 2048) return;
    int b = c >> 9;
    int rest = c & 511;
    int oc = rest >> 2, q = rest & 3;
    int py = (q >> 1) * 4, px = (q & 1) * 4;
    const float* p = f5 + ((size_t)(b * 128 + oc)) * 64;
    float s = 0.f;
    #pragma unroll
    for (int dy = 0; dy < 4; dy++)
        #pragma unroll
        for (int dx = 0; dx < 4; dx++)
            s += p[(py + dy) * 8 + px + dx];
    codes[c] = s * (1.f / 16.f);
}

// ---------------- heads: weights = codes@lw.T+lb ; vertices = pad(cumsum(softmax(...))) ----
__global__ void k_head(const float* __restrict__ codes, const float* __restrict__ lw,
                       const float* __restrict__ lb, const float* __restrict__ aw,
                       const float* __restrict__ ab, float* __restrict__ wt,
                       float* __restrict__ vert, float* __restrict__ out_w,
                       float* __restrict__ out_v) {
    int blk = blockIdx.x;
    int t = threadIdx.x;  // 64 threads
    if (blk == 12) {
        if (t < 12) {
            int b = t / 3, j = t % 3;
            const float* c = codes + b * 512;
            const float* l = lw + j * 512;
            float s = lb[j];
            for (int k = 0; k < 512; k++) s += c[k] * l[k];
            wt[t] = s;
            out_w[t] = s;
        }
        return;
    }
    int b = blk / 3, ch = blk % 3;
    __shared__ float y[32];
    if (t < 32) {
        const float* c = codes + b * 512;
        const float* a = aw + (size_t)(ch * 32 + t) * 512;
        float s = ab[ch * 32 + t];
        for (int k = 0; k < 512; k++) s += c[k] * a[k];
        y[t] = s;
    }
    __syncthreads();
    if (t == 0) {
        float mx = y[0];
        for (int m = 1; m < 32; m++) mx = fmaxf(mx, y[m]);
        float e[32];
        float sum = 0.f;
        for (int m = 0; m < 32; m++) { e[m] = expf(y[m] - mx); sum += e[m]; }
        float inv = 1.f / sum;
        float cum = 0.f;
        float* vb = vert + (b * 3 + ch) * 33;
        float* ob = out_v + (b * 3 + ch) * 33;
        vb[0] = 0.f; ob[0] = 0.f;
        for (int m = 0; m < 32; m++) { cum += e[m] * inv; vb[m + 1] = cum; ob[m + 1] = cum; }
    }
}

// ---------------- LUT generation: luts[b] = bw @ wt[b], relayout to [D][D][D] x float4 -----
__global__ void k_lutgen(const float* __restrict__ bw, const float* __restrict__ wt,
                         float* __restrict__ luts4) {
    int gid = blockIdx.x * 256 + threadIdx.x;     // over 4*35937
    if (gid >= BATCH * LUT_D3) return;
    int b = gid / LUT_D3;
    int cell = gid - b * LUT_D3;
    float w0 = wt[b * 3], w1 = wt[b * 3 + 1], w2 = wt[b * 3 + 2];
    const float* r0 = bw + (size_t)(0 * LUT_D3 + cell) * 3;
    const float* r1 = bw + (size_t)(1 * LUT_D3 + cell) * 3;
    const float* r2 = bw + (size_t)(2 * LUT_D3 + cell) * 3;
    float4 o;
    o.x = r0[0] * w0 + r0[1] * w1 + r0[2] * w2;
    o.y = r1[0] * w0 + r1[1] * w1 + r1[2] * w2;
    o.z = r2[0] * w0 + r2[1] * w1 + r2[2] * w2;
    o.w = 0.f;
    ((float4*)luts4)[gid] = o;
}

// ---------------- per-pixel searchsorted + trilinear LUT sample ----------------------------
__device__ __forceinline__ void search1(const float* __restrict__ sv, int ch, float x,
                                        int& i0, float& f) {
    const float* v = sv + ch * LUT_D;
    int lo = 0, hi = LUT_D;
    while (lo < hi) { int mid = (lo + hi) >> 1; if (v[mid] <= x) lo = mid + 1; else hi = mid; }
    int idx = lo < 1 ? 1 : (lo > LUT_D - 1 ? LUT_D - 1 : lo);
    float vl = v[idx - 1], vh = v[idx];
    float fr = (x - vl) / (vh - vl + 1e-8f);
    float coord = (float)(idx - 1) + fr;
    coord = fminf(fmaxf(coord, 0.f), (float)(LUT_D - 1));
    i0 = (int)floorf(coord);
    if (i0 > LUT_D - 2) i0 = LUT_D - 2;
    f = coord - (float)i0;
}

__global__ void __launch_bounds__(256) k_transform(const float* __restrict__ lq,
                                                   const float* __restrict__ luts4,
                                                   const float* __restrict__ vert,
                                                   float* __restrict__ out) {
    int bimg = blockIdx.x >> 10;                  // 1024 blocks per image
    int blk  = blockIdx.x & 1023;
    __shared__ float sv[3 * LUT_D];
    if (threadIdx.x < 3 * LUT_D) sv[threadIdx.x] = vert[bimg * 3 * LUT_D + threadIdx.x];
    __syncthreads();
    int p0 = blk * 1024 + threadIdx.x * 4;        // 4 px per thread
    const float* lr = lq + (size_t)bimg * 3 * HW_IMG + p0;
    float4 r4 = *(const float4*)(lr);
    float4 g4 = *(const float4*)(lr + HW_IMG);
    float4 b4 = *(const float4*)(lr + 2 * HW_IMG);
    const float4* L = (const float4*)(luts4 + (size_t)bimg * LUT_D3 * 4);
    float rr[4] = {r4.x, r4.y, r4.z, r4.w};
    float gg[4] = {g4.x, g4.y, g4.z, g4.w};
    float bb[4] = {b4.x, b4.y, b4.z, b4.w};
    float ro[4], go[4], bo[4];
    #pragma unroll
    for (int i = 0; i < 4; i++) {
        int i0, j0, k0; float fr, fg, fb;
        search1(sv, 0, rr[i], i0, fr);
        search1(sv, 1, gg[i], j0, fg);
        search1(sv, 2, bb[i], k0, fb);
        int base = (i0 * LUT_D + j0) * LUT_D + k0;
        float4 q000 = L[base],        q001 = L[base + 1];
        float4 q010 = L[base + 33],   q011 = L[base + 34];
        float4 q100 = L[base + 1089], q101 = L[base + 1090];
        float4 q110 = L[base + 1122], q111 = L[base + 1123];
        float w000 = (1.f - fr) * (1.f - fg) * (1.f - fb), w001 = (1.f - fr) * (1.f - fg) * fb;
        float w010 = (1.f - fr) * fg * (1.f - fb),         w011 = (1.f - fr) * fg * fb;
        float w100 = fr * (1.f - fg) * (1.f - fb),         w101 = fr * (1.f - fg) * fb;
        float w110 = fr * fg * (1.f - fb),                 w111 = fr * fg * fb;
        float rx = q000.x*w000 + q001.x*w001 + q010.x*w010 + q011.x*w011
                 + q100.x*w100 + q101.x*w101 + q110.x*w110 + q111.x*w111;
        float ry = q000.y*w000 + q001.y*w001 + q010.y*w010 + q011.y*w011
                 + q100.y*w100 + q101.y*w101 + q110.y*w110 + q111.y*w111;
        float rz = q000.z*w000 + q001.z*w001 + q010.z*w010 + q011.z*w011
                 + q100.z*w100 + q101.z*w101 + q110.z*w110 + q111.z*w111;
        ro[i] = fminf(fmaxf(rx, 0.f), 1.f);
        go[i] = fminf(fmaxf(ry, 0.f), 1.f);
        bo[i] = fminf(fmaxf(rz, 0.f), 1.f);
    }
    float* op = out + (size_t)bimg * 3 * HW_IMG + p0;
    float4 o0 = {ro[0], ro[1], ro[2], ro[3]};
    float4 o1 = {go[0], go[1], go[2], go[3]};
    float4 o2 = {bo[0], bo[1], bo[2], bo[3]};
    *(float4*)(op) = o0;
    *(float4*)(op + HW_IMG) = o1;
    *(float4*)(op + 2 * HW_IMG) = o2;
}

extern "C" void kernel_launch(void* const* d_in, const int* in_sizes, int n_in,
                              void* d_out, int out_size, void* d_ws, size_t ws_size,
                              hipStream_t stream) {
    const float* lq  = (const float*)d_in[0];
    const float* w1  = (const float*)d_in[1];
    const float* b1  = (const float*)d_in[2];
    const float* g1  = (const float*)d_in[3];
    const float* be1 = (const float*)d_in[4];
    const float* w2  = (const float*)d_in[5];
    const float* b2  = (const float*)d_in[6];
    const float* g2  = (const float*)d_in[7];
    const float* be2 = (const float*)d_in[8];
    const float* w3  = (const float*)d_in[9];
    const float* b3  = (const float*)d_in[10];
    const float* g3  = (const float*)d_in[11];
    const float* be3 = (const float*)d_in[12];
    const float* w4  = (const float*)d_in[13];
    const float* b4  = (const float*)d_in[14];
    const float* g4  = (const float*)d_in[15];
    const float* be4 = (const float*)d_in[16];
    const float* w5  = (const float*)d_in[17];
    const float* b5  = (const float*)d_in[18];
    const float* lw  = (const float*)d_in[19];
    const float* lb  = (const float*)d_in[20];
    const float* bw  = (const float*)d_in[21];
    const float* aw  = (const float*)d_in[22];
    const float* ab  = (const float*)d_in[23];

    float* ws     = (float*)d_ws;
    float* r256   = ws;                    // 786432
    float* f1     = r256 + 786432;         // 1048576
    float* f2     = f1 + 1048576;          // 524288
    float* f3     = f2 + 524288;           // 262144
    float* f4     = f3 + 262144;           // 131072
    float* f5     = f4 + 131072;           // 32768 (4x128x8x8)
    float* codes  = f5 + 32768;            // 2048
    float* wt     = codes + 2048;          // 12
    float* vert   = wt + 12;               // 396
    float* stats  = vert + 396;            // 1920 floats of stats
    float* stats1 = stats;                 // 4*16*2  = 128
    float* stats2 = stats1 + 128;          // 4*32*2  = 256
    float* stats3 = stats2 + 256;          // 4*64*2  = 512
    float* stats4 = stats3 + 512;          // 4*128*2 = 1024
    float* part1  = stats + 1920;          // 64*256*2  = 32768
    float* part2  = part1 + 32768;         // 128*64*2  = 16384
    float* part3  = part2 + 16384;         // 256*16*2  = 8192
    float* part4  = part3 + 8192;          // 512*4*2   = 4096
    float* luts4  = part4 + 4096;          // 4*35937*4; offset 2851096 % 4 == 0 (16B aligned)

    float* outs  = (float*)d_out;
    float* out_w = outs + (size_t)BATCH * 3 * HW_IMG;  // 12582912
    float* out_v = out_w + 12;

    k_resize<<<3072, 256, 0, stream>>>(lq, r256);
    // S1: in [4,3,256,256] -> f1 [4,16,128,128]; grid 4*16*16*1 = 1024
    k_conv_t<3, 16, 128, 128, false, true><<<1024, 256, 0, stream>>>(
        r256, nullptr, nullptr, nullptr, w1, b1, f1, part1);
    k_stats<256><<<64, 64, 0, stream>>>(part1, stats1);
    // S2: -> f2 [4,32,64,64]; grid 4*8*8*2 = 512
    k_conv_t<16, 32, 64, 64, true, true><<<512, 256, 0, stream>>>(
        f1, stats1, g1, be1, w2, b2, f2, part2);
    k_stats<64><<<128, 64, 0, stream>>>(part2, stats2);
    // S3: -> f3 [4,64,32,32]; grid 4*4*4*4 = 256
    k_conv_t<32, 64, 32, 32, true, true><<<256, 256, 0, stream>>>(
        f2, stats2, g2, be2, w3, b3, f3, part3);
    k_stats<16><<<256, 64, 0, stream>>>(part3, stats3);
    // S4: -> f4 [4,128,16,16]; grid 4*2*2*8 = 128
    k_conv_t<64, 128, 16, 16, true, true><<<128, 256, 0, stream>>>(
        f3, stats3, g3, be3, w4, b4, f4, part4);
    k_stats<4><<<512, 64, 0, stream>>>(part4, stats4);
    // S5: -> f5 [4,128,8,8]; grid 4*1*1*8 = 32 (no IN after; input normed with stats4)
    k_conv_t<128, 128, 8, 8, true, false><<<32, 256, 0, stream>>>(
        f4, stats4, g4, be4, w5, b5, f5, nullptr);
    k_pool<<<8, 256, 0, stream>>>(f5, codes);
    k_head<<<13, 64, 0, stream>>>(codes, lw, lb, aw, ab, wt, vert, out_w, out_v);
    k_lutgen<<<(BATCH * LUT_D3 + 255) / 256, 256, 0, stream>>>(bw, wt, luts4);
    k_transform<<<BATCH * 1024, 256, 0, stream>>>(lq, luts4, vert, outs);
}

// Round 5
// 320.531 us; speedup vs baseline: 3.1609x; 1.3984x over previous
//
#include <hip/hip_runtime.h>
#include <math.h>

#define LUT_D 33
#define LUT_D3 35937   // 33^3
#define NEG 0.2f
#define BATCH 4
#define HW_IMG 1048576 // 1024*1024

// ---------------- resize 1024 -> 256 (half-pixel bilinear, scale 4 => frac=0.5) -------------
__global__ void k_resize(const float* __restrict__ lq, float* __restrict__ out) {
    int gid = blockIdx.x * 256 + threadIdx.x;     // over 4*3*256*256 = 786432
    if (gid >= BATCH * 3 * 256 * 256) return;
    int x  = gid & 255;
    int y  = (gid >> 8) & 255;
    int pc = gid >> 16;                            // b*3 + c
    const float* in = lq + (size_t)pc * HW_IMG;
    const float* p0 = in + (4 * y + 1) * 1024 + (4 * x + 1);
    out[gid] = 0.25f * (p0[0] + p0[1] + p0[1024] + p0[1025]);
}

// ---------------- tiled conv3x3 s2 p1 (+LeakyReLU if NSPLIT==1), fused input-norm -----------
// block = (b, ty, tx, icc, ocg); 256 threads = 64 px * 4 oc-lanes (4 oc each).
// LDS tile rows: [pad pad pad | halo | 16 aligned floats] stride 20 -> float4 staging.
// NSPLIT>1: block computes partial over its ic-slice, writes raw partials (k_combine finishes).
// NORM_IN: input normalized on the fly via precomputed (sc,sh) pairs in nrm_in.
// STATS_OUT (NSPLIT==1 only): per-(oc,tile) wave partial sums of activated outputs.
template<int IC, int OC, int OH, int OW, int NSPLIT, bool NORM_IN, bool STATS_OUT>
__global__ void __launch_bounds__(256) k_conv_t(
    const float* __restrict__ in, const float* __restrict__ nrm_in,
    const float* __restrict__ w, const float* __restrict__ bias,
    float* __restrict__ out, float* __restrict__ part) {
    constexpr int IH = OH * 2, IW = OW * 2;
    constexpr int ICB = IC / NSPLIT;              // <= 32
    constexpr int TROW = 20, TSZ = 17 * TROW;     // 340 floats per ic tile
    constexpr int WQ = ICB * 9 / 4;               // float4s per oc (when sliced); int only if ICB*9%4==0... handled below
    constexpr int NTX = OW / 8, NTY = OH / 8, NOCG = OC / 16;
    constexpr int NT = NTX * NTY;
    constexpr int PX = OH * OW;

    __shared__ float sIn[ICB * TSZ];
    __shared__ float swl[16 * ICB * 9];
    __shared__ float sNm[NORM_IN ? ICB * 2 : 1];

    int id = blockIdx.x;
    int ocg   = id % NOCG;   id /= NOCG;
    int icc_i = id % NSPLIT; id /= NSPLIT;
    int tx    = id % NTX;    id /= NTX;
    int ty    = id % NTY;    id /= NTY;
    int b     = id;
    int icc   = icc_i * ICB;

    int t    = threadIdx.x;
    int lane = t >> 6;          // 0..3
    int px   = t & 63;
    int py   = px >> 3, pxx = px & 7;
    int oc0  = ocg * 16 + lane * 4;

    // ---- stage weights (vectorized) + norm pairs ----
    if (IC == ICB) {
        const float4* wsrc = (const float4*)(w + (size_t)ocg * 16 * IC * 9);
        for (int i = t; i < 16 * IC * 9 / 4; i += 256) ((float4*)swl)[i] = wsrc[i];
    } else {
        // per-oc contiguous slice [ICB*9], 16B-aligned (ICB=32 -> 288 floats = 72 float4)
        for (int i = t; i < 16 * WQ; i += 256) {
            int ol = i / WQ, qi = i % WQ;
            ((float4*)swl)[ol * WQ + qi] =
                *(const float4*)(w + ((size_t)(ocg * 16 + ol) * IC + icc) * 9 + qi * 4);
        }
    }
    if (NORM_IN) {
        for (int i = t; i < ICB * 2; i += 256) sNm[i] = nrm_in[(b * IC + icc) * 2 + i];
    }
    __syncthreads();

    // ---- stage input tile: 4 float4 + 1 halo scalar per (ic,row) ----
    int iy0 = ty * 16 - 1;
    int xbase = tx * 16;
    const float* inb = in + (size_t)(b * IC + icc) * (IH * IW);
    for (int q = t; q < ICB * 17 * 4; q += 256) {
        int ic_l = q / 68;
        int r    = q % 68;
        int row  = r >> 2, quad = r & 3;
        int iy = iy0 + row;
        float4 v = {0.f, 0.f, 0.f, 0.f};
        if (iy >= 0 && iy < IH) {
            v = *(const float4*)(inb + (size_t)ic_l * (IH * IW) + (size_t)iy * IW + xbase + quad * 4);
            if (NORM_IN) {
                float sc = sNm[ic_l * 2], sh = sNm[ic_l * 2 + 1];
                v.x = v.x * sc + sh; v.y = v.y * sc + sh;
                v.z = v.z * sc + sh; v.w = v.w * sc + sh;
            }
        }
        *(float4*)(sIn + ic_l * TSZ + row * TROW + 4 + quad * 4) = v;
    }
    for (int h = t; h < ICB * 17; h += 256) {
        int ic_l = h / 17, row = h % 17;
        int iy = iy0 + row, ix = xbase - 1;
        float v = 0.f;
        if (iy >= 0 && iy < IH && ix >= 0) {
            v = inb[(size_t)ic_l * (IH * IW) + (size_t)iy * IW + ix];
            if (NORM_IN) v = v * sNm[ic_l * 2] + sNm[ic_l * 2 + 1];
        }
        sIn[ic_l * TSZ + row * TROW + 3] = v;
    }
    __syncthreads();

    // ---- compute ----
    float acc[4];
    #pragma unroll
    for (int j = 0; j < 4; j++) acc[j] = (NSPLIT == 1) ? bias[oc0 + j] : 0.f;

    for (int i2 = 0; i2 < ICB; i2++) {
        const float* tp = sIn + i2 * TSZ + py * 2 * TROW + pxx * 2 + 3;
        float x0 = tp[0],        x1 = tp[1],        x2 = tp[2];
        float x3 = tp[TROW],     x4 = tp[TROW + 1], x5 = tp[TROW + 2];
        float x6 = tp[2 * TROW], x7 = tp[2 * TROW + 1], x8 = tp[2 * TROW + 2];
        #pragma unroll
        for (int j = 0; j < 4; j++) {
            const float* wp = swl + ((lane * 4 + j) * ICB + i2) * 9;
            acc[j] = fmaf(x0, wp[0], acc[j]);
            acc[j] = fmaf(x1, wp[1], acc[j]);
            acc[j] = fmaf(x2, wp[2], acc[j]);
            acc[j] = fmaf(x3, wp[3], acc[j]);
            acc[j] = fmaf(x4, wp[4], acc[j]);
            acc[j] = fmaf(x5, wp[5], acc[j]);
            acc[j] = fmaf(x6, wp[6], acc[j]);
            acc[j] = fmaf(x7, wp[7], acc[j]);
            acc[j] = fmaf(x8, wp[8], acc[j]);
        }
    }

    int oy = ty * 8 + py, ox = tx * 8 + pxx;
    if (NSPLIT == 1) {
        int tile = ty * NTX + tx;
        #pragma unroll
        for (int j = 0; j < 4; j++) {
            float a = acc[j];
            a = a >= 0.f ? a : NEG * a;
            out[((size_t)(b * OC + oc0 + j) * OH + oy) * OW + ox] = a;
            if (STATS_OUT) {
                float s1 = a, s2 = a * a;
                for (int off = 32; off > 0; off >>= 1) {
                    s1 += __shfl_down(s1, off, 64);
                    s2 += __shfl_down(s2, off, 64);
                }
                if (px == 0) {
                    size_t pi = ((size_t)(b * OC + oc0 + j) * NT + tile) * 2;
                    part[pi] = s1; part[pi + 1] = s2;
                }
            }
        }
    } else {
        #pragma unroll
        for (int j = 0; j < 4; j++) {
            part[(size_t)icc_i * (BATCH * OC * PX) +
                 (size_t)(b * OC + oc0 + j) * PX + oy * OW + ox] = acc[j];
        }
    }
}

// ---------------- combine ic-split partials: + bias, LeakyReLU, optional stats -------------
template<int NSPLIT, int OC, int PX, bool STATS>
__global__ void k_combine(const float* __restrict__ ps, const float* __restrict__ bias,
                          float* __restrict__ out, float* __restrict__ spart) {
    constexpr int TOT = BATCH * OC * PX;
    int e = blockIdx.x * 256 + threadIdx.x;
    if (e >= TOT) return;
    float s = 0.f;
    #pragma unroll
    for (int k = 0; k < NSPLIT; k++) s += ps[(size_t)k * TOT + e];
    int oc = (e / PX) % OC;
    s += bias[oc];
    s = s >= 0.f ? s : NEG * s;
    out[e] = s;
    if (STATS) {
        float s1 = s, s2 = s * s;
        for (int off = 32; off > 0; off >>= 1) {
            s1 += __shfl_down(s1, off, 64);
            s2 += __shfl_down(s2, off, 64);
        }
        if ((threadIdx.x & 63) == 0) {
            int widx = e >> 6;   // == (b*OC+oc)*(PX/64) + wave-in-plane
            spart[widx * 2] = s1; spart[widx * 2 + 1] = s2;
        }
    }
}

// ---------------- reduce partial (s1,s2) -> per-(b,c) norm pair (scale, shift) -------------
template<int NT>
__global__ void k_norm(const float* __restrict__ part, const float* __restrict__ g,
                       const float* __restrict__ be, float invN, int C,
                       float* __restrict__ nrm) {
    int bc = blockIdx.x;
    int t  = threadIdx.x;  // 64
    float s1 = 0.f, s2 = 0.f;
    for (int i = t; i < NT; i += 64) {
        s1 += part[((size_t)bc * NT + i) * 2];
        s2 += part[((size_t)bc * NT + i) * 2 + 1];
    }
    #pragma unroll
    for (int off = 32; off > 0; off >>= 1) {
        s1 += __shfl_down(s1, off, 64);
        s2 += __shfl_down(s2, off, 64);
    }
    if (t == 0) {
        int c = bc % C;
        float m   = s1 * invN;
        float var = s2 * invN - m * m;
        float sc  = g[c] * rsqrtf(var + 1e-5f);
        nrm[bc * 2]     = sc;
        nrm[bc * 2 + 1] = be[c] - m * sc;
    }
}

// ---------------- AdaptiveAvgPool2d(2) on [4,128,8,8] -> codes [4,512] ---------------------
__global__ void k_pool(const float* __restrict__ f5, float* __restrict__ codes) {
    int c = blockIdx.x * 256 + threadIdx.x;   // 2048
    if (c >= 2048) return;
    int b = c >> 9;
    int rest = c & 511;
    int oc = rest >> 2, q = rest & 3;
    int py = (q >> 1) * 4, px = (q & 1) * 4;
    const float* p = f5 + ((size_t)(b * 128 + oc)) * 64;
    float s = 0.f;
    #pragma unroll
    for (int dy = 0; dy < 4; dy++)
        #pragma unroll
        for (int dx = 0; dx < 4; dx++)
            s += p[(py + dy) * 8 + px + dx];
    codes[c] = s * (1.f / 16.f);
}

// ---------------- heads: weights = codes@lw.T+lb ; vertices = pad(cumsum(softmax(...))) ----
__global__ void k_head(const float* __restrict__ codes, const float* __restrict__ lw,
                       const float* __restrict__ lb, const float* __restrict__ aw,
                       const float* __restrict__ ab, float* __restrict__ wt,
                       float* __restrict__ vert, float* __restrict__ out_w,
                       float* __restrict__ out_v) {
    int blk = blockIdx.x;
    int t = threadIdx.x;  // 64 threads
    if (blk == 12) {
        if (t < 12) {
            int b = t / 3, j = t % 3;
            const float* c = codes + b * 512;
            const float* l = lw + j * 512;
            float s = lb[j];
            for (int k = 0; k < 512; k++) s += c[k] * l[k];
            wt[t] = s;
            out_w[t] = s;
        }
        return;
    }
    int b = blk / 3, ch = blk % 3;
    __shared__ float y[32];
    if (t < 32) {
        const float* c = codes + b * 512;
        const float* a = aw + (size_t)(ch * 32 + t) * 512;
        float s = ab[ch * 32 + t];
        for (int k = 0; k < 512; k++) s += c[k] * a[k];
        y[t] = s;
    }
    __syncthreads();
    if (t == 0) {
        float mx = y[0];
        for (int m = 1; m < 32; m++) mx = fmaxf(mx, y[m]);
        float e[32];
        float sum = 0.f;
        for (int m = 0; m < 32; m++) { e[m] = expf(y[m] - mx); sum += e[m]; }
        float inv = 1.f / sum;
        float cum = 0.f;
        float* vb = vert + (b * 3 + ch) * 33;
        float* ob = out_v + (b * 3 + ch) * 33;
        vb[0] = 0.f; ob[0] = 0.f;
        for (int m = 0; m < 32; m++) { cum += e[m] * inv; vb[m + 1] = cum; ob[m + 1] = cum; }
    }
}

// ---------------- LUT generation: luts[b] = bw @ wt[b], relayout to [D][D][D] x float4 -----
__global__ void k_lutgen(const float* __restrict__ bw, const float* __restrict__ wt,
                         float* __restrict__ luts4) {
    int gid = blockIdx.x * 256 + threadIdx.x;     // over 4*35937
    if (gid >= BATCH * LUT_D3) return;
    int b = gid / LUT_D3;
    int cell = gid - b * LUT_D3;
    float w0 = wt[b * 3], w1 = wt[b * 3 + 1], w2 = wt[b * 3 + 2];
    const float* r0 = bw + (size_t)(0 * LUT_D3 + cell) * 3;
    const float* r1 = bw + (size_t)(1 * LUT_D3 + cell) * 3;
    const float* r2 = bw + (size_t)(2 * LUT_D3 + cell) * 3;
    float4 o;
    o.x = r0[0] * w0 + r0[1] * w1 + r0[2] * w2;
    o.y = r1[0] * w0 + r1[1] * w1 + r1[2] * w2;
    o.z = r2[0] * w0 + r2[1] * w1 + r2[2] * w2;
    o.w = 0.f;
    ((float4*)luts4)[gid] = o;
}

// ---------------- per-pixel searchsorted + trilinear LUT sample ----------------------------
__device__ __forceinline__ void search1(const float* __restrict__ sv, int ch, float x,
                                        int& i0, float& f) {
    const float* v = sv + ch * LUT_D;
    int lo = 0, hi = LUT_D;
    while (lo < hi) { int mid = (lo + hi) >> 1; if (v[mid] <= x) lo = mid + 1; else hi = mid; }
    int idx = lo < 1 ? 1 : (lo > LUT_D - 1 ? LUT_D - 1 : lo);
    float vl = v[idx - 1], vh = v[idx];
    float fr = (x - vl) / (vh - vl + 1e-8f);
    float coord = (float)(idx - 1) + fr;
    coord = fminf(fmaxf(coord, 0.f), (float)(LUT_D - 1));
    i0 = (int)floorf(coord);
    if (i0 > LUT_D - 2) i0 = LUT_D - 2;
    f = coord - (float)i0;
}

__global__ void __launch_bounds__(256) k_transform(const float* __restrict__ lq,
                                                   const float* __restrict__ luts4,
                                                   const float* __restrict__ vert,
                                                   float* __restrict__ out) {
    int bimg = blockIdx.x >> 10;                  // 1024 blocks per image
    int blk  = blockIdx.x & 1023;
    __shared__ float sv[3 * LUT_D];
    if (threadIdx.x < 3 * LUT_D) sv[threadIdx.x] = vert[bimg * 3 * LUT_D + threadIdx.x];
    __syncthreads();
    int p0 = blk * 1024 + threadIdx.x * 4;        // 4 px per thread
    const float* lr = lq + (size_t)bimg * 3 * HW_IMG + p0;
    float4 r4 = *(const float4*)(lr);
    float4 g4 = *(const float4*)(lr + HW_IMG);
    float4 b4 = *(const float4*)(lr + 2 * HW_IMG);
    const float4* L = (const float4*)(luts4 + (size_t)bimg * LUT_D3 * 4);
    float rr[4] = {r4.x, r4.y, r4.z, r4.w};
    float gg[4] = {g4.x, g4.y, g4.z, g4.w};
    float bb[4] = {b4.x, b4.y, b4.z, b4.w};
    float ro[4], go[4], bo[4];
    #pragma unroll
    for (int i = 0; i < 4; i++) {
        int i0, j0, k0; float fr, fg, fb;
        search1(sv, 0, rr[i], i0, fr);
        search1(sv, 1, gg[i], j0, fg);
        search1(sv, 2, bb[i], k0, fb);
        int base = (i0 * LUT_D + j0) * LUT_D + k0;
        float4 q000 = L[base],        q001 = L[base + 1];
        float4 q010 = L[base + 33],   q011 = L[base + 34];
        float4 q100 = L[base + 1089], q101 = L[base + 1090];
        float4 q110 = L[base + 1122], q111 = L[base + 1123];
        float w000 = (1.f - fr) * (1.f - fg) * (1.f - fb), w001 = (1.f - fr) * (1.f - fg) * fb;
        float w010 = (1.f - fr) * fg * (1.f - fb),         w011 = (1.f - fr) * fg * fb;
        float w100 = fr * (1.f - fg) * (1.f - fb),         w101 = fr * (1.f - fg) * fb;
        float w110 = fr * fg * (1.f - fb),                 w111 = fr * fg * fb;
        float rx = q000.x*w000 + q001.x*w001 + q010.x*w010 + q011.x*w011
                 + q100.x*w100 + q101.x*w101 + q110.x*w110 + q111.x*w111;
        float ry = q000.y*w000 + q001.y*w001 + q010.y*w010 + q011.y*w011
                 + q100.y*w100 + q101.y*w101 + q110.y*w110 + q111.y*w111;
        float rz = q000.z*w000 + q001.z*w001 + q010.z*w010 + q011.z*w011
                 + q100.z*w100 + q101.z*w101 + q110.z*w110 + q111.z*w111;
        ro[i] = fminf(fmaxf(rx, 0.f), 1.f);
        go[i] = fminf(fmaxf(ry, 0.f), 1.f);
        bo[i] = fminf(fmaxf(rz, 0.f), 1.f);
    }
    float* op = out + (size_t)bimg * 3 * HW_IMG + p0;
    float4 o0 = {ro[0], ro[1], ro[2], ro[3]};
    float4 o1 = {go[0], go[1], go[2], go[3]};
    float4 o2 = {bo[0], bo[1], bo[2], bo[3]};
    *(float4*)(op) = o0;
    *(float4*)(op + HW_IMG) = o1;
    *(float4*)(op + 2 * HW_IMG) = o2;
}

extern "C" void kernel_launch(void* const* d_in, const int* in_sizes, int n_in,
                              void* d_out, int out_size, void* d_ws, size_t ws_size,
                              hipStream_t stream) {
    const float* lq  = (const float*)d_in[0];
    const float* w1  = (const float*)d_in[1];
    const float* b1  = (const float*)d_in[2];
    const float* g1  = (const float*)d_in[3];
    const float* be1 = (const float*)d_in[4];
    const float* w2  = (const float*)d_in[5];
    const float* b2  = (const float*)d_in[6];
    const float* g2  = (const float*)d_in[7];
    const float* be2 = (const float*)d_in[8];
    const float* w3  = (const float*)d_in[9];
    const float* b3  = (const float*)d_in[10];
    const float* g3  = (const float*)d_in[11];
    const float* be3 = (const float*)d_in[12];
    const float* w4  = (const float*)d_in[13];
    const float* b4  = (const float*)d_in[14];
    const float* g4  = (const float*)d_in[15];
    const float* be4 = (const float*)d_in[16];
    const float* w5  = (const float*)d_in[17];
    const float* b5  = (const float*)d_in[18];
    const float* lw  = (const float*)d_in[19];
    const float* lb  = (const float*)d_in[20];
    const float* bw  = (const float*)d_in[21];
    const float* aw  = (const float*)d_in[22];
    const float* ab  = (const float*)d_in[23];

    float* ws     = (float*)d_ws;
    float* r256   = ws;                    // 786432
    float* f1     = r256 + 786432;         // 1048576 (dead after S2; psplit4/5 aliased here)
    float* f2     = f1 + 1048576;          // 524288
    float* f3     = f2 + 524288;           // 262144
    float* f4     = f3 + 262144;           // 131072
    float* f5     = f4 + 131072;           // 32768 (4x128x8x8)
    float* codes  = f5 + 32768;            // 2048
    float* wt     = codes + 2048;          // 12
    float* vert   = wt + 12;               // 396
    float* part1  = vert + 396;            // 64 planes * 256 tiles * 2  = 32768
    float* part2  = part1 + 32768;         // 128 * 64 * 2 = 16384
    float* part3  = part2 + 16384;         // 256 * 16 * 2 = 8192
    float* spart4 = part3 + 8192;          // 512 * 4 * 2  = 4096
    float* norm1  = spart4 + 4096;         // 4*16*2  = 128
    float* norm2  = norm1 + 128;           // 4*32*2  = 256
    float* norm3  = norm2 + 256;           // 4*64*2  = 512
    float* norm4  = norm3 + 512;           // 4*128*2 = 1024
    float* luts4  = norm4 + 1024;          // 4*35937*4; byte offset 2851096*4 % 16 == 0
    float* psplit4 = f1;                   // 2*131072 = 262144 (alias, f1 dead by S4)
    float* psplit5 = f1 + 262144;          // 4*32768  = 131072

    float* outs  = (float*)d_out;
    float* out_w = outs + (size_t)BATCH * 3 * HW_IMG;  // 12582912
    float* out_v = out_w + 12;

    k_resize<<<3072, 256, 0, stream>>>(lq, r256);
    // S1: [4,3,256,256] -> f1 [4,16,128,128]; grid b*ty*tx*split*ocg = 4*16*16*1*1 = 1024
    k_conv_t<3, 16, 128, 128, 1, false, true><<<1024, 256, 0, stream>>>(
        r256, nullptr, w1, b1, f1, part1);
    k_norm<256><<<64, 64, 0, stream>>>(part1, g1, be1, 1.f / 16384.f, 16, norm1);
    // S2: -> f2 [4,32,64,64]; grid 4*8*8*1*2 = 512
    k_conv_t<16, 32, 64, 64, 1, true, true><<<512, 256, 0, stream>>>(
        f1, norm1, w2, b2, f2, part2);
    k_norm<64><<<128, 64, 0, stream>>>(part2, g2, be2, 1.f / 4096.f, 32, norm2);
    // S3: -> f3 [4,64,32,32]; grid 4*4*4*1*4 = 256
    k_conv_t<32, 64, 32, 32, 1, true, true><<<256, 256, 0, stream>>>(
        f2, norm2, w3, b3, f3, part3);
    k_norm<16><<<256, 64, 0, stream>>>(part3, g3, be3, 1.f / 1024.f, 64, norm3);
    // S4: -> psplit4; grid 4*2*2*2*8 = 256; combine -> f4 [4,128,16,16] + stats
    k_conv_t<64, 128, 16, 16, 2, true, false><<<256, 256, 0, stream>>>(
        f3, norm3, w4, b4, nullptr, psplit4);
    k_combine<2, 128, 256, true><<<512, 256, 0, stream>>>(psplit4, b4, f4, spart4);
    k_norm<4><<<512, 64, 0, stream>>>(spart4, g4, be4, 1.f / 256.f, 128, norm4);
    // S5: -> psplit5; grid 4*1*1*4*8 = 128; combine -> f5 [4,128,8,8] (no IN)
    k_conv_t<128, 128, 8, 8, 4, true, false><<<128, 256, 0, stream>>>(
        f4, norm4, w5, b5, nullptr, psplit5);
    k_combine<4, 128, 64, false><<<128, 256, 0, stream>>>(psplit5, b5, f5, nullptr);
    k_pool<<<8, 256, 0, stream>>>(f5, codes);
    k_head<<<13, 64, 0, stream>>>(codes, lw, lb, aw, ab, wt, vert, out_w, out_v);
    k_lutgen<<<(BATCH * LUT_D3 + 255) / 256, 256, 0, stream>>>(bw, wt, luts4);
    k_transform<<<BATCH * 1024, 256, 0, stream>>>(lq, luts4, vert, outs);
}

// Round 6
// 310.925 us; speedup vs baseline: 3.2586x; 1.0309x over previous
//
#include <hip/hip_runtime.h>
#include <hip/hip_fp16.h>
#include <math.h>

#define LUT_D 33
#define LUT_D3 35937   // 33^3
#define NEG 0.2f
#define BATCH 4
#define HW_IMG 1048576 // 1024*1024

// ---------------- resize 1024 -> 256 (half-pixel bilinear, scale 4 => frac=0.5) -------------
__global__ void k_resize(const float* __restrict__ lq, float* __restrict__ out) {
    int gid = blockIdx.x * 256 + threadIdx.x;     // over 4*3*256*256 = 786432
    if (gid >= BATCH * 3 * 256 * 256) return;
    int x  = gid & 255;
    int y  = (gid >> 8) & 255;
    int pc = gid >> 16;                            // b*3 + c
    const float* in = lq + (size_t)pc * HW_IMG;
    const float* p0 = in + (4 * y + 1) * 1024 + (4 * x + 1);
    out[gid] = 0.25f * (p0[0] + p0[1] + p0[1024] + p0[1025]);
}

// ---------------- tiled conv3x3 s2 p1 (+LeakyReLU if NSPLIT==1), fused input-norm -----------
// block = (b, ty, tx, icc, ocg); 256 threads = 64 px * 4 oc-lanes (4 oc each).
// LDS tile rows: [pad pad pad | halo | 16 aligned floats] stride 20 -> float4 staging.
// NSPLIT>1: block computes partial over its ic-slice, writes raw partials (k_combine finishes).
// NORM_IN: input normalized on the fly via precomputed (sc,sh) pairs in nrm_in.
// STATS_OUT (NSPLIT==1 only): per-(oc,tile) wave partial sums of activated outputs.
template<int IC, int OC, int OH, int OW, int NSPLIT, bool NORM_IN, bool STATS_OUT>
__global__ void __launch_bounds__(256) k_conv_t(
    const float* __restrict__ in, const float* __restrict__ nrm_in,
    const float* __restrict__ w, const float* __restrict__ bias,
    float* __restrict__ out, float* __restrict__ part) {
    constexpr int IH = OH * 2, IW = OW * 2;
    constexpr int ICB = IC / NSPLIT;              // <= 32
    constexpr int TROW = 20, TSZ = 17 * TROW;     // 340 floats per ic tile
    constexpr int WQ = ICB * 9 / 4;               // float4s per oc slice
    constexpr int NTX = OW / 8, NTY = OH / 8, NOCG = OC / 16;
    constexpr int NT = NTX * NTY;
    constexpr int PX = OH * OW;

    __shared__ float sIn[ICB * TSZ];
    __shared__ float swl[16 * ICB * 9];
    __shared__ float sNm[NORM_IN ? ICB * 2 : 1];

    int id = blockIdx.x;
    int ocg   = id % NOCG;   id /= NOCG;
    int icc_i = id % NSPLIT; id /= NSPLIT;
    int tx    = id % NTX;    id /= NTX;
    int ty    = id % NTY;    id /= NTY;
    int b     = id;
    int icc   = icc_i * ICB;

    int t    = threadIdx.x;
    int lane = t >> 6;          // 0..3
    int px   = t & 63;
    int py   = px >> 3, pxx = px & 7;
    int oc0  = ocg * 16 + lane * 4;

    // ---- stage weights (vectorized) + norm pairs ----
    if (IC == ICB) {
        const float4* wsrc = (const float4*)(w + (size_t)ocg * 16 * IC * 9);
        for (int i = t; i < 16 * IC * 9 / 4; i += 256) ((float4*)swl)[i] = wsrc[i];
    } else {
        for (int i = t; i < 16 * WQ; i += 256) {
            int ol = i / WQ, qi = i % WQ;
            ((float4*)swl)[ol * WQ + qi] =
                *(const float4*)(w + ((size_t)(ocg * 16 + ol) * IC + icc) * 9 + qi * 4);
        }
    }
    if (NORM_IN) {
        for (int i = t; i < ICB * 2; i += 256) sNm[i] = nrm_in[(b * IC + icc) * 2 + i];
    }
    __syncthreads();

    // ---- stage input tile: 4 float4 + 1 halo scalar per (ic,row) ----
    int iy0 = ty * 16 - 1;
    int xbase = tx * 16;
    const float* inb = in + (size_t)(b * IC + icc) * (IH * IW);
    for (int q = t; q < ICB * 17 * 4; q += 256) {
        int ic_l = q / 68;
        int r    = q % 68;
        int row  = r >> 2, quad = r & 3;
        int iy = iy0 + row;
        float4 v = {0.f, 0.f, 0.f, 0.f};
        if (iy >= 0 && iy < IH) {
            v = *(const float4*)(inb + (size_t)ic_l * (IH * IW) + (size_t)iy * IW + xbase + quad * 4);
            if (NORM_IN) {
                float sc = sNm[ic_l * 2], sh = sNm[ic_l * 2 + 1];
                v.x = v.x * sc + sh; v.y = v.y * sc + sh;
                v.z = v.z * sc + sh; v.w = v.w * sc + sh;
            }
        }
        *(float4*)(sIn + ic_l * TSZ + row * TROW + 4 + quad * 4) = v;
    }
    for (int h = t; h < ICB * 17; h += 256) {
        int ic_l = h / 17, row = h % 17;
        int iy = iy0 + row, ix = xbase - 1;
        float v = 0.f;
        if (iy >= 0 && iy < IH && ix >= 0) {
            v = inb[(size_t)ic_l * (IH * IW) + (size_t)iy * IW + ix];
            if (NORM_IN) v = v * sNm[ic_l * 2] + sNm[ic_l * 2 + 1];
        }
        sIn[ic_l * TSZ + row * TROW + 3] = v;
    }
    __syncthreads();

    // ---- compute ----
    float acc[4];
    #pragma unroll
    for (int j = 0; j < 4; j++) acc[j] = (NSPLIT == 1) ? bias[oc0 + j] : 0.f;

    for (int i2 = 0; i2 < ICB; i2++) {
        const float* tp = sIn + i2 * TSZ + py * 2 * TROW + pxx * 2 + 3;
        float x0 = tp[0],        x1 = tp[1],        x2 = tp[2];
        float x3 = tp[TROW],     x4 = tp[TROW + 1], x5 = tp[TROW + 2];
        float x6 = tp[2 * TROW], x7 = tp[2 * TROW + 1], x8 = tp[2 * TROW + 2];
        #pragma unroll
        for (int j = 0; j < 4; j++) {
            const float* wp = swl + ((lane * 4 + j) * ICB + i2) * 9;
            acc[j] = fmaf(x0, wp[0], acc[j]);
            acc[j] = fmaf(x1, wp[1], acc[j]);
            acc[j] = fmaf(x2, wp[2], acc[j]);
            acc[j] = fmaf(x3, wp[3], acc[j]);
            acc[j] = fmaf(x4, wp[4], acc[j]);
            acc[j] = fmaf(x5, wp[5], acc[j]);
            acc[j] = fmaf(x6, wp[6], acc[j]);
            acc[j] = fmaf(x7, wp[7], acc[j]);
            acc[j] = fmaf(x8, wp[8], acc[j]);
        }
    }

    int oy = ty * 8 + py, ox = tx * 8 + pxx;
    if (NSPLIT == 1) {
        int tile = ty * NTX + tx;
        #pragma unroll
        for (int j = 0; j < 4; j++) {
            float a = acc[j];
            a = a >= 0.f ? a : NEG * a;
            out[((size_t)(b * OC + oc0 + j) * OH + oy) * OW + ox] = a;
            if (STATS_OUT) {
                float s1 = a, s2 = a * a;
                for (int off = 32; off > 0; off >>= 1) {
                    s1 += __shfl_down(s1, off, 64);
                    s2 += __shfl_down(s2, off, 64);
                }
                if (px == 0) {
                    size_t pi = ((size_t)(b * OC + oc0 + j) * NT + tile) * 2;
                    part[pi] = s1; part[pi + 1] = s2;
                }
            }
        }
    } else {
        #pragma unroll
        for (int j = 0; j < 4; j++) {
            part[(size_t)icc_i * (BATCH * OC * PX) +
                 (size_t)(b * OC + oc0 + j) * PX + oy * OW + ox] = acc[j];
        }
    }
}

// ---------------- combine ic-split partials: + bias, LeakyReLU, optional stats -------------
template<int NSPLIT, int OC, int PX, bool STATS>
__global__ void k_combine(const float* __restrict__ ps, const float* __restrict__ bias,
                          float* __restrict__ out, float* __restrict__ spart) {
    constexpr int TOT = BATCH * OC * PX;
    int e = blockIdx.x * 256 + threadIdx.x;
    if (e >= TOT) return;
    float s = 0.f;
    #pragma unroll
    for (int k = 0; k < NSPLIT; k++) s += ps[(size_t)k * TOT + e];
    int oc = (e / PX) % OC;
    s += bias[oc];
    s = s >= 0.f ? s : NEG * s;
    out[e] = s;
    if (STATS) {
        float s1 = s, s2 = s * s;
        for (int off = 32; off > 0; off >>= 1) {
            s1 += __shfl_down(s1, off, 64);
            s2 += __shfl_down(s2, off, 64);
        }
        if ((threadIdx.x & 63) == 0) {
            int widx = e >> 6;
            spart[widx * 2] = s1; spart[widx * 2 + 1] = s2;
        }
    }
}

// ---------------- reduce partial (s1,s2) -> per-(b,c) norm pair (scale, shift) -------------
template<int NT>
__global__ void k_norm(const float* __restrict__ part, const float* __restrict__ g,
                       const float* __restrict__ be, float invN, int C,
                       float* __restrict__ nrm) {
    int bc = blockIdx.x;
    int t  = threadIdx.x;  // 64
    float s1 = 0.f, s2 = 0.f;
    for (int i = t; i < NT; i += 64) {
        s1 += part[((size_t)bc * NT + i) * 2];
        s2 += part[((size_t)bc * NT + i) * 2 + 1];
    }
    #pragma unroll
    for (int off = 32; off > 0; off >>= 1) {
        s1 += __shfl_down(s1, off, 64);
        s2 += __shfl_down(s2, off, 64);
    }
    if (t == 0) {
        int c = bc % C;
        float m   = s1 * invN;
        float var = s2 * invN - m * m;
        float sc  = g[c] * rsqrtf(var + 1e-5f);
        nrm[bc * 2]     = sc;
        nrm[bc * 2 + 1] = be[c] - m * sc;
    }
}

// ---------------- AdaptiveAvgPool2d(2) on [4,128,8,8] -> codes [4,512] ---------------------
__global__ void k_pool(const float* __restrict__ f5, float* __restrict__ codes) {
    int c = blockIdx.x * 256 + threadIdx.x;   // 2048
    if (c >= 2048) return;
    int b = c >> 9;
    int rest = c & 511;
    int oc = rest >> 2, q = rest & 3;
    int py = (q >> 1) * 4, px = (q & 1) * 4;
    const float* p = f5 + ((size_t)(b * 128 + oc)) * 64;
    float s = 0.f;
    #pragma unroll
    for (int dy = 0; dy < 4; dy++)
        #pragma unroll
        for (int dx = 0; dx < 4; dx++)
            s += p[(py + dy) * 8 + px + dx];
    codes[c] = s * (1.f / 16.f);
}

// ---------------- heads: weights = codes@lw.T+lb ; vertices = pad(cumsum(softmax(...))) ----
__global__ void k_head(const float* __restrict__ codes, const float* __restrict__ lw,
                       const float* __restrict__ lb, const float* __restrict__ aw,
                       const float* __restrict__ ab, float* __restrict__ wt,
                       float* __restrict__ vert, float* __restrict__ out_w,
                       float* __restrict__ out_v) {
    int blk = blockIdx.x;
    int t = threadIdx.x;  // 64 threads
    if (blk == 12) {
        if (t < 12) {
            int b = t / 3, j = t % 3;
            const float* c = codes + b * 512;
            const float* l = lw + j * 512;
            float s = lb[j];
            for (int k = 0; k < 512; k++) s += c[k] * l[k];
            wt[t] = s;
            out_w[t] = s;
        }
        return;
    }
    int b = blk / 3, ch = blk % 3;
    __shared__ float y[32];
    if (t < 32) {
        const float* c = codes + b * 512;
        const float* a = aw + (size_t)(ch * 32 + t) * 512;
        float s = ab[ch * 32 + t];
        for (int k = 0; k < 512; k++) s += c[k] * a[k];
        y[t] = s;
    }
    __syncthreads();
    if (t == 0) {
        float mx = y[0];
        for (int m = 1; m < 32; m++) mx = fmaxf(mx, y[m]);
        float e[32];
        float sum = 0.f;
        for (int m = 0; m < 32; m++) { e[m] = expf(y[m] - mx); sum += e[m]; }
        float inv = 1.f / sum;
        float cum = 0.f;
        float* vb = vert + (b * 3 + ch) * 33;
        float* ob = out_v + (b * 3 + ch) * 33;
        vb[0] = 0.f; ob[0] = 0.f;
        for (int m = 0; m < 32; m++) { cum += e[m] * inv; vb[m + 1] = cum; ob[m + 1] = cum; }
    }
}

// ---------------- LUT generation: fp16 blue-pair entries ------------------------------------
// entry[(i*33+j)*33+k] = halves [r(k),g(k),b(k),r(k+1),g(k+1),b(k+1),0,0]  (16 B)
__global__ void k_lutgen(const float* __restrict__ bw, const float* __restrict__ wt,
                         float4* __restrict__ lutp) {
    int gid = blockIdx.x * 256 + threadIdx.x;     // over 4*35937
    if (gid >= BATCH * LUT_D3) return;
    int b = gid / LUT_D3;
    int cell = gid - b * LUT_D3;
    int k = cell % LUT_D;
    int cn = (k < LUT_D - 1) ? cell + 1 : cell;
    float w0 = wt[b * 3], w1 = wt[b * 3 + 1], w2 = wt[b * 3 + 2];
    const float* r0p = bw + (size_t)(0 * LUT_D3 + cell) * 3;
    const float* g0p = bw + (size_t)(1 * LUT_D3 + cell) * 3;
    const float* b0p = bw + (size_t)(2 * LUT_D3 + cell) * 3;
    const float* r1p = bw + (size_t)(0 * LUT_D3 + cn) * 3;
    const float* g1p = bw + (size_t)(1 * LUT_D3 + cn) * 3;
    const float* b1p = bw + (size_t)(2 * LUT_D3 + cn) * 3;
    union { float4 f4; __half h[8]; } u;
    u.h[0] = __float2half_rn(r0p[0] * w0 + r0p[1] * w1 + r0p[2] * w2);
    u.h[1] = __float2half_rn(g0p[0] * w0 + g0p[1] * w1 + g0p[2] * w2);
    u.h[2] = __float2half_rn(b0p[0] * w0 + b0p[1] * w1 + b0p[2] * w2);
    u.h[3] = __float2half_rn(r1p[0] * w0 + r1p[1] * w1 + r1p[2] * w2);
    u.h[4] = __float2half_rn(g1p[0] * w0 + g1p[1] * w1 + g1p[2] * w2);
    u.h[5] = __float2half_rn(b1p[0] * w0 + b1p[1] * w1 + b1p[2] * w2);
    u.h[6] = __float2half_rn(0.f);
    u.h[7] = __float2half_rn(0.f);
    lutp[gid] = u.f4;
}

// ---------------- per-pixel searchsorted + trilinear LUT sample ----------------------------
__device__ __forceinline__ void search1(const float* __restrict__ sv, int ch, float x,
                                        int& i0, float& f) {
    const float* v = sv + ch * LUT_D;
    int lo = 0, hi = LUT_D;
    while (lo < hi) { int mid = (lo + hi) >> 1; if (v[mid] <= x) lo = mid + 1; else hi = mid; }
    int idx = lo < 1 ? 1 : (lo > LUT_D - 1 ? LUT_D - 1 : lo);
    float vl = v[idx - 1], vh = v[idx];
    float fr = (x - vl) / (vh - vl + 1e-8f);
    float coord = (float)(idx - 1) + fr;
    coord = fminf(fmaxf(coord, 0.f), (float)(LUT_D - 1));
    i0 = (int)floorf(coord);
    if (i0 > LUT_D - 2) i0 = LUT_D - 2;
    f = coord - (float)i0;
}

// decode fp16 blue-pair entry, lerp along blue
__device__ __forceinline__ void decode_lerp(float4 e, float fb,
                                            float& rv, float& gv, float& bv) {
    union { float f; __half2 h; } u0, u1, u2;
    u0.f = e.x; u1.f = e.y; u2.f = e.z;
    float2 a = __half22float2(u0.h);   // r0, g0
    float2 b = __half22float2(u1.h);   // b0, r1
    float2 c = __half22float2(u2.h);   // g1, b1
    rv = fmaf(fb, b.y - a.x, a.x);
    gv = fmaf(fb, c.x - a.y, a.y);
    bv = fmaf(fb, c.y - b.x, b.x);
}

__global__ void __launch_bounds__(256) k_transform(const float* __restrict__ lq,
                                                   const float4* __restrict__ lutp,
                                                   const float* __restrict__ vert,
                                                   float* __restrict__ out) {
    int bimg = blockIdx.x >> 10;                  // 1024 blocks per image
    int blk  = blockIdx.x & 1023;
    __shared__ float sv[3 * LUT_D];
    if (threadIdx.x < 3 * LUT_D) sv[threadIdx.x] = vert[bimg * 3 * LUT_D + threadIdx.x];
    __syncthreads();
    int p0 = blk * 1024 + threadIdx.x * 4;        // 4 px per thread
    const float* lr = lq + (size_t)bimg * 3 * HW_IMG + p0;
    float4 r4 = *(const float4*)(lr);
    float4 g4 = *(const float4*)(lr + HW_IMG);
    float4 b4 = *(const float4*)(lr + 2 * HW_IMG);
    const float4* L = lutp + (size_t)bimg * LUT_D3;
    float rr[4] = {r4.x, r4.y, r4.z, r4.w};
    float gg[4] = {g4.x, g4.y, g4.z, g4.w};
    float bb[4] = {b4.x, b4.y, b4.z, b4.w};
    float ro[4], go[4], bo[4];
    #pragma unroll
    for (int i = 0; i < 4; i++) {
        int i0, j0, k0; float fr, fg, fb;
        search1(sv, 0, rr[i], i0, fr);
        search1(sv, 1, gg[i], j0, fg);
        search1(sv, 2, bb[i], k0, fb);
        int base = (i0 * LUT_D + j0) * LUT_D + k0;
        float4 e00 = L[base];            // (i0, j0)
        float4 e01 = L[base + 33];       // (i0, j0+1)
        float4 e10 = L[base + 1089];     // (i0+1, j0)
        float4 e11 = L[base + 1122];     // (i0+1, j0+1)
        float r00, g00, b00, r01, g01, b01, r10, g10, b10, r11, g11, b11;
        decode_lerp(e00, fb, r00, g00, b00);
        decode_lerp(e01, fb, r01, g01, b01);
        decode_lerp(e10, fb, r10, g10, b10);
        decode_lerp(e11, fb, r11, g11, b11);
        float w00 = (1.f - fr) * (1.f - fg), w01 = (1.f - fr) * fg;
        float w10 = fr * (1.f - fg),         w11 = fr * fg;
        float rx = r00 * w00 + r01 * w01 + r10 * w10 + r11 * w11;
        float ry = g00 * w00 + g01 * w01 + g10 * w10 + g11 * w11;
        float rz = b00 * w00 + b01 * w01 + b10 * w10 + b11 * w11;
        ro[i] = fminf(fmaxf(rx, 0.f), 1.f);
        go[i] = fminf(fmaxf(ry, 0.f), 1.f);
        bo[i] = fminf(fmaxf(rz, 0.f), 1.f);
    }
    float* op = out + (size_t)bimg * 3 * HW_IMG + p0;
    float4 o0 = {ro[0], ro[1], ro[2], ro[3]};
    float4 o1 = {go[0], go[1], go[2], go[3]};
    float4 o2 = {bo[0], bo[1], bo[2], bo[3]};
    *(float4*)(op) = o0;
    *(float4*)(op + HW_IMG) = o1;
    *(float4*)(op + 2 * HW_IMG) = o2;
}

extern "C" void kernel_launch(void* const* d_in, const int* in_sizes, int n_in,
                              void* d_out, int out_size, void* d_ws, size_t ws_size,
                              hipStream_t stream) {
    const float* lq  = (const float*)d_in[0];
    const float* w1  = (const float*)d_in[1];
    const float* b1  = (const float*)d_in[2];
    const float* g1  = (const float*)d_in[3];
    const float* be1 = (const float*)d_in[4];
    const float* w2  = (const float*)d_in[5];
    const float* b2  = (const float*)d_in[6];
    const float* g2  = (const float*)d_in[7];
    const float* be2 = (const float*)d_in[8];
    const float* w3  = (const float*)d_in[9];
    const float* b3  = (const float*)d_in[10];
    const float* g3  = (const float*)d_in[11];
    const float* be3 = (const float*)d_in[12];
    const float* w4  = (const float*)d_in[13];
    const float* b4  = (const float*)d_in[14];
    const float* g4  = (const float*)d_in[15];
    const float* be4 = (const float*)d_in[16];
    const float* w5  = (const float*)d_in[17];
    const float* b5  = (const float*)d_in[18];
    const float* lw  = (const float*)d_in[19];
    const float* lb  = (const float*)d_in[20];
    const float* bw  = (const float*)d_in[21];
    const float* aw  = (const float*)d_in[22];
    const float* ab  = (const float*)d_in[23];

    float* ws     = (float*)d_ws;
    float* r256   = ws;                    // 786432
    float* f1     = r256 + 786432;         // 1048576 (dead after S2; psplit4/5 aliased here)
    float* f2     = f1 + 1048576;          // 524288
    float* f3     = f2 + 524288;           // 262144
    float* f4     = f3 + 262144;           // 131072
    float* f5     = f4 + 131072;           // 32768 (4x128x8x8)
    float* codes  = f5 + 32768;            // 2048
    float* wt     = codes + 2048;          // 12
    float* vert   = wt + 12;               // 396
    float* part1  = vert + 396;            // 64 planes * 256 tiles * 2  = 32768
    float* part2  = part1 + 32768;         // 128 * 64 * 2 = 16384
    float* part3  = part2 + 16384;         // 256 * 16 * 2 = 8192
    float* spart4 = part3 + 8192;          // 512 * 4 * 2  = 4096
    float* norm1  = spart4 + 4096;         // 4*16*2  = 128
    float* norm2  = norm1 + 128;           // 4*32*2  = 256
    float* norm3  = norm2 + 256;           // 4*64*2  = 512
    float* norm4  = norm3 + 512;           // 4*128*2 = 1024
    float* luts4  = norm4 + 1024;          // 4*35937 float4 entries; 16B aligned
    float* psplit4 = f1;                   // 2*131072 = 262144 (alias, f1 dead by S4)
    float* psplit5 = f1 + 262144;          // 4*32768  = 131072

    float* outs  = (float*)d_out;
    float* out_w = outs + (size_t)BATCH * 3 * HW_IMG;  // 12582912
    float* out_v = out_w + 12;

    k_resize<<<3072, 256, 0, stream>>>(lq, r256);
    // S1: [4,3,256,256] -> f1 [4,16,128,128]; grid 4*16*16*1*1 = 1024
    k_conv_t<3, 16, 128, 128, 1, false, true><<<1024, 256, 0, stream>>>(
        r256, nullptr, w1, b1, f1, part1);
    k_norm<256><<<64, 64, 0, stream>>>(part1, g1, be1, 1.f / 16384.f, 16, norm1);
    // S2: -> f2 [4,32,64,64]; grid 4*8*8*1*2 = 512
    k_conv_t<16, 32, 64, 64, 1, true, true><<<512, 256, 0, stream>>>(
        f1, norm1, w2, b2, f2, part2);
    k_norm<64><<<128, 64, 0, stream>>>(part2, g2, be2, 1.f / 4096.f, 32, norm2);
    // S3: -> f3 [4,64,32,32]; grid 4*4*4*1*4 = 256
    k_conv_t<32, 64, 32, 32, 1, true, true><<<256, 256, 0, stream>>>(
        f2, norm2, w3, b3, f3, part3);
    k_norm<16><<<256, 64, 0, stream>>>(part3, g3, be3, 1.f / 1024.f, 64, norm3);
    // S4: -> psplit4; grid 4*2*2*2*8 = 256; combine -> f4 [4,128,16,16] + stats
    k_conv_t<64, 128, 16, 16, 2, true, false><<<256, 256, 0, stream>>>(
        f3, norm3, w4, b4, nullptr, psplit4);
    k_combine<2, 128, 256, true><<<512, 256, 0, stream>>>(psplit4, b4, f4, spart4);
    k_norm<4><<<512, 64, 0, stream>>>(spart4, g4, be4, 1.f / 256.f, 128, norm4);
    // S5: -> psplit5; grid 4*1*1*4*8 = 128; combine -> f5 [4,128,8,8] (no IN)
    k_conv_t<128, 128, 8, 8, 4, true, false><<<128, 256, 0, stream>>>(
        f4, norm4, w5, b5, nullptr, psplit5);
    k_combine<4, 128, 64, false><<<128, 256, 0, stream>>>(psplit5, b5, f5, nullptr);
    k_pool<<<8, 256, 0, stream>>>(f5, codes);
    k_head<<<13, 64, 0, stream>>>(codes, lw, lb, aw, ab, wt, vert, out_w, out_v);
    k_lutgen<<<(BATCH * LUT_D3 + 255) / 256, 256, 0, stream>>>(bw, wt, (float4*)luts4);
    k_transform<<<BATCH * 1024, 256, 0, stream>>>(lq, (const float4*)luts4, vert, outs);
}